// Round 1
// baseline (367.762 us; speedup 1.0000x reference)
//
#include <hip/hip_runtime.h>

typedef __attribute__((ext_vector_type(8))) short short8;
typedef __attribute__((ext_vector_type(4))) float f32x4;

#define BB 16
#define MM 2048
#define NN 2048

static __device__ __forceinline__ unsigned short f2bf(float f) {
  union { float f; unsigned int u; } c; c.f = f;
  unsigned int u = c.u;
  return (unsigned short)((u + 0x7FFFu + ((u >> 16) & 1u)) >> 16);
}

// in: [B, nrows, 64] f32 -> out: [B, 64, nrows] bf16
__global__ void transpose_cvt(const float* __restrict__ in,
                              unsigned short* __restrict__ out, int nrows) {
  __shared__ float t[64][65];
  int b = blockIdx.y;
  int n0 = blockIdx.x * 64;
  int tid = threadIdx.x;
  int lane = tid & 63;
  int q = tid >> 6;
  const float* inb = in + ((size_t)b * nrows + n0) * 64;
#pragma unroll
  for (int i = 0; i < 16; ++i) {
    int n = q * 16 + i;
    t[n][lane] = inb[n * 64 + lane];
  }
  __syncthreads();
  unsigned short* outb = out + (size_t)b * 64 * nrows + n0;
  int pr = tid & 31, rq = tid >> 5;
#pragma unroll
  for (int i = 0; i < 8; ++i) {
    int r = rq + 8 * i;
    int n = 2 * pr;
    unsigned int pk = (unsigned int)f2bf(t[n][r]) | ((unsigned int)f2bf(t[n + 1][r]) << 16);
    *(unsigned int*)(outb + (size_t)r * nrows + n) = pk;
  }
}

// Gram: bmat[b] += chunk of T * T^T where T = [64, K] bf16 (row-major).
// A[row][k] = T[row][k], B[k][col] = T[col][k] -> same fragment loads.
// grid (8, B), block 256 (4 waves, wave w does rows w*16..+15)
__global__ void gemm_gram(const unsigned short* __restrict__ tT,
                          float* __restrict__ bmat, int K) {
  int b = blockIdx.y;
  int chunk = K >> 3;
  int k0 = blockIdx.x * chunk;
  int tid = threadIdx.x;
  int w = tid >> 6, l = tid & 63;
  int lr = l & 15, g = l >> 4;
  const unsigned short* vb = tT + (size_t)b * 64 * K;
  f32x4 acc[4] = {};
  for (int kk = 0; kk < chunk; kk += 32) {
    int k = k0 + kk + 8 * g;
    short8 fr = *(const short8*)(vb + (size_t)(w * 16 + lr) * K + k);
#pragma unroll
    for (int ct = 0; ct < 4; ++ct) {
      short8 fc = *(const short8*)(vb + (size_t)(ct * 16 + lr) * K + k);
      acc[ct] = __builtin_amdgcn_mfma_f32_16x16x32_bf16(fr, fc, acc[ct], 0, 0, 0);
    }
  }
  float* bb = bmat + b * 4096;
#pragma unroll
  for (int ct = 0; ct < 4; ++ct)
#pragma unroll
    for (int j = 0; j < 4; ++j)
      atomicAdd(&bb[(w * 16 + 4 * g + j) * 64 + ct * 16 + lr], acc[ct][j]);
}

// a[b][m][r] = sum_n x[b][m][n] * v[b][n][r];  vT = [B,64,N] bf16
// grid (M/64, B), block 256; wave w: rows w*16..+15, all 64 cols
__global__ void gemm_xv(const float* __restrict__ x,
                        const unsigned short* __restrict__ vT,
                        float* __restrict__ a) {
  int b = blockIdx.y;
  int m0 = blockIdx.x * 64;
  int tid = threadIdx.x;
  int w = tid >> 6, l = tid & 63;
  int lr = l & 15, g = l >> 4;
  const float* xrow = x + (size_t)b * MM * NN + (size_t)(m0 + w * 16 + lr) * NN;
  const unsigned short* vb = vT + (size_t)b * 64 * NN;
  f32x4 acc[4] = {};
#pragma unroll 2
  for (int k0 = 0; k0 < NN; k0 += 32) {
    int k = k0 + 8 * g;
    const float4* xp = (const float4*)(xrow + k);
    float4 x0 = xp[0], x1 = xp[1];
    short8 af;
    af[0] = (short)f2bf(x0.x); af[1] = (short)f2bf(x0.y);
    af[2] = (short)f2bf(x0.z); af[3] = (short)f2bf(x0.w);
    af[4] = (short)f2bf(x1.x); af[5] = (short)f2bf(x1.y);
    af[6] = (short)f2bf(x1.z); af[7] = (short)f2bf(x1.w);
#pragma unroll
    for (int ct = 0; ct < 4; ++ct) {
      short8 bf = *(const short8*)(vb + (size_t)(ct * 16 + lr) * NN + k);
      acc[ct] = __builtin_amdgcn_mfma_f32_16x16x32_bf16(af, bf, acc[ct], 0, 0, 0);
    }
  }
  float* ab = a + ((size_t)b * MM + m0 + w * 16) * 64;
#pragma unroll
  for (int ct = 0; ct < 4; ++ct)
#pragma unroll
    for (int j = 0; j < 4; ++j)
      ab[(size_t)(4 * g + j) * 64 + ct * 16 + lr] = acc[ct][j];
}

// a[b][n][r] = sum_m x[b][m][n] * u[b][m][r];  uT = [B,64,M] bf16
// A = x^T staged via XOR-swizzled LDS (bf16 [64 n][64 m], row stride 128B)
// grid (N/64, B), block 256
__global__ void gemm_xtu(const float* __restrict__ x,
                         const unsigned short* __restrict__ uT,
                         float* __restrict__ a) {
  __shared__ unsigned short xt[64 * 64];
  int b = blockIdx.y;
  int n0 = blockIdx.x * 64;
  int tid = threadIdx.x;
  int w = tid >> 6, l = tid & 63;
  int lr = l & 15, g = l >> 4;
  const float* xb = x + (size_t)b * MM * NN;
  const unsigned short* ub = uT + (size_t)b * 64 * MM;
  f32x4 acc[4] = {};
  int sn = tid & 63;
  int sm0 = (tid >> 6) * 2;
  int nrow = w * 16 + lr;  // this lane's A row (n within tile)
  for (int k0 = 0; k0 < MM; k0 += 64) {
    __syncthreads();
#pragma unroll
    for (int i = 0; i < 8; ++i) {
      int m = sm0 + i * 8;
      float v0 = xb[(size_t)(k0 + m) * NN + n0 + sn];
      float v1 = xb[(size_t)(k0 + m + 1) * NN + n0 + sn];
      unsigned int pk = (unsigned int)f2bf(v0) | ((unsigned int)f2bf(v1) << 16);
      *(unsigned int*)((char*)xt + (sn * 128 + ((2 * m) ^ ((sn & 7) << 4)))) = pk;
    }
    __syncthreads();
#pragma unroll
    for (int kh = 0; kh < 2; ++kh) {
      int byteoff = nrow * 128 + ((kh * 64 + g * 16) ^ ((lr & 7) << 4));
      short8 af = *(const short8*)((const char*)xt + byteoff);
      int k = k0 + kh * 32 + 8 * g;
#pragma unroll
      for (int ct = 0; ct < 4; ++ct) {
        short8 bf = *(const short8*)(ub + (size_t)(ct * 16 + lr) * MM + k);
        acc[ct] = __builtin_amdgcn_mfma_f32_16x16x32_bf16(af, bf, acc[ct], 0, 0, 0);
      }
    }
  }
  float* ab = a + ((size_t)b * NN + n0 + w * 16) * 64;
#pragma unroll
  for (int ct = 0; ct < 4; ++ct)
#pragma unroll
    for (int j = 0; j < 4; ++j)
      ab[(size_t)(4 * g + j) * 64 + ct * 16 + lr] = acc[ct][j];
}

// Coordinate descent: one wave per row. lane c owns u[c], a[c], g[c].
// g[c] = sum_j u_cur[j]*b[j][c], maintained incrementally.
// grid (nrows/4, B), block 256 (4 waves)
__global__ void cd_kernel(const float* __restrict__ u_in,
                          const float* __restrict__ a_ws,
                          const float* __restrict__ bmat,
                          float* __restrict__ u_out,
                          float l1, float l2e, int nrows) {
  __shared__ float bs[4096];
  int b = blockIdx.y;
  int tid = threadIdx.x;
  for (int i = tid; i < 4096; i += 256) bs[i] = bmat[b * 4096 + i];
  __syncthreads();
  int w = tid >> 6, c = tid & 63;
  int m = blockIdx.x * 4 + w;
  size_t base = ((size_t)b * nrows + m) * 64;
  float u_c = u_in[base + c];
  float a_c = a_ws[base + c];
  float g_c = 0.f;
#pragma unroll 8
  for (int j = 0; j < 64; ++j) {
    float uj = __shfl(u_c, j);
    g_c = fmaf(uj, bs[j * 64 + c], g_c);
  }
#pragma unroll 4
  for (int r = 0; r < 64; ++r) {
    float brc = bs[r * 64 + c];
    float t2 = g_c - u_c * brc;             // on lane r: g[r] - u_old[r]*b_rr
    float num = a_c - t2;
    float st = copysignf(fmaxf(fabsf(num) - l1, 0.f), num);
    float unew = st / (brc + l2e);          // on lane r: correct new value
    float delta = unew - u_c;
    delta = __shfl(delta, r);               // broadcast lane r's delta
    if (c == r) u_c += delta;
    g_c = fmaf(delta, brc, g_c);
  }
  u_out[base + c] = u_c;
}

extern "C" void kernel_launch(void* const* d_in, const int* in_sizes, int n_in,
                              void* d_out, int out_size, void* d_ws, size_t ws_size,
                              hipStream_t stream) {
  (void)in_sizes; (void)n_in; (void)out_size; (void)ws_size;
  const float* x = (const float*)d_in[0];
  const float* u = (const float*)d_in[1];
  const float* v = (const float*)d_in[2];
  float* u_out = (float*)d_out;
  float* v_out = u_out + (size_t)BB * MM * 64;

  float* a_ws = (float*)d_ws;                                        // 8.39 MB
  float* b_ws = (float*)((char*)d_ws + (size_t)BB * MM * 64 * 4);    // 256 KB
  unsigned short* tT = (unsigned short*)((char*)b_ws + (size_t)BB * 4096 * 4);  // 4.19 MB

  float l1u = (float)(0.01 * 0.1 * (double)NN);
  float l2u = (float)(0.01 * 0.9 * (double)NN + 1e-16);
  float l1v = (float)(0.01 * 0.1 * (double)MM);
  float l2v = (float)(0.01 * 0.9 * (double)MM + 1e-16);

  // ---- factor 0: update u ----
  hipMemsetAsync(b_ws, 0, (size_t)BB * 4096 * 4, stream);
  transpose_cvt<<<dim3(NN / 64, BB), 256, 0, stream>>>(v, tT, NN);
  gemm_gram<<<dim3(8, BB), 256, 0, stream>>>(tT, b_ws, NN);
  gemm_xv<<<dim3(MM / 64, BB), 256, 0, stream>>>(x, tT, a_ws);
  cd_kernel<<<dim3(MM / 4, BB), 256, 0, stream>>>(u, a_ws, b_ws, u_out, l1u, l2u, MM);

  // ---- factor 1: update v (uses new u) ----
  hipMemsetAsync(b_ws, 0, (size_t)BB * 4096 * 4, stream);
  transpose_cvt<<<dim3(MM / 64, BB), 256, 0, stream>>>(u_out, tT, MM);
  gemm_gram<<<dim3(8, BB), 256, 0, stream>>>(tT, b_ws, MM);
  gemm_xtu<<<dim3(NN / 64, BB), 256, 0, stream>>>(x, tT, a_ws);
  cd_kernel<<<dim3(NN / 4, BB), 256, 0, stream>>>(v, a_ws, b_ws, v_out, l1v, l2v, NN);
}

// Round 2
// 349.491 us; speedup vs baseline: 1.0523x; 1.0523x over previous
//
#include <hip/hip_runtime.h>

typedef __attribute__((ext_vector_type(8))) short short8;
typedef __attribute__((ext_vector_type(4))) float f32x4;

#define BB 16
#define MM 2048
#define NN 2048

static __device__ __forceinline__ unsigned int cvtpk(float lo, float hi) {
  unsigned int r;
  asm("v_cvt_pk_bf16_f32 %0, %1, %2" : "=v"(r) : "v"(lo), "v"(hi));
  return r;
}

// in: [B, nrows, 64] f32 -> out: [B, 64, nrows] bf16
__global__ void transpose_cvt(const float* __restrict__ in,
                              unsigned short* __restrict__ out, int nrows) {
  __shared__ float t[64][65];
  int b = blockIdx.y;
  int n0 = blockIdx.x * 64;
  int tid = threadIdx.x;
  int lane = tid & 63;
  int q = tid >> 6;
  const float* inb = in + ((size_t)b * nrows + n0) * 64;
#pragma unroll
  for (int i = 0; i < 16; ++i) {
    int n = q * 16 + i;
    t[n][lane] = inb[n * 64 + lane];
  }
  __syncthreads();
  unsigned short* outb = out + (size_t)b * 64 * nrows + n0;
  int pr = tid & 31, rq = tid >> 5;
#pragma unroll
  for (int i = 0; i < 8; ++i) {
    int r = rq + 8 * i;
    int n = 2 * pr;
    *(unsigned int*)(outb + (size_t)r * nrows + n) = cvtpk(t[n][r], t[n + 1][r]);
  }
}

// Gram: bmat[b] += chunk of T * T^T where T = [64, K] bf16 (row-major).
// grid (16, B), block 256 (4 waves)
__global__ void gemm_gram(const unsigned short* __restrict__ tT,
                          float* __restrict__ bmat, int K) {
  int b = blockIdx.y;
  int chunk = K >> 4;
  int k0 = blockIdx.x * chunk;
  int tid = threadIdx.x;
  int w = tid >> 6, l = tid & 63;
  int lr = l & 15, g = l >> 4;
  const unsigned short* vb = tT + (size_t)b * 64 * K;
  f32x4 acc[4] = {};
  for (int kk = 0; kk < chunk; kk += 32) {
    int k = k0 + kk + 8 * g;
    short8 fr = *(const short8*)(vb + (size_t)(w * 16 + lr) * K + k);
#pragma unroll
    for (int ct = 0; ct < 4; ++ct) {
      short8 fc = *(const short8*)(vb + (size_t)(ct * 16 + lr) * K + k);
      acc[ct] = __builtin_amdgcn_mfma_f32_16x16x32_bf16(fr, fc, acc[ct], 0, 0, 0);
    }
  }
  float* bb = bmat + b * 4096;
#pragma unroll
  for (int ct = 0; ct < 4; ++ct)
#pragma unroll
    for (int j = 0; j < 4; ++j)
      atomicAdd(&bb[(w * 16 + 4 * g + j) * 64 + ct * 16 + lr], acc[ct][j]);
}

// a[b][m][r] = sum_n x[b][m][n] * v[b][n][r];  vT = [B,64,N] bf16
// grid (M/64, B), block 512 = 8 waves: waves 0-3 K-half 0, waves 4-7 K-half 1
__global__ void __launch_bounds__(512, 4)
gemm_xv(const float* __restrict__ x,
        const unsigned short* __restrict__ vT,
        float* __restrict__ a) {
  __shared__ float red[4][16][66];
  int b = blockIdx.y;
  int m0 = blockIdx.x * 64;
  int tid = threadIdx.x;
  int w = tid >> 6, l = tid & 63;
  int lr = l & 15, g = l >> 4;
  int half = w >> 2, wq = w & 3;
  const float* xrow = x + (size_t)b * MM * NN + (size_t)(m0 + wq * 16 + lr) * NN + half * (NN / 2);
  const unsigned short* vb = vT + (size_t)b * 64 * NN + half * (NN / 2);
  f32x4 acc[4] = {};
#pragma unroll 4
  for (int k0 = 0; k0 < NN / 2; k0 += 32) {
    int k = k0 + 8 * g;
    const float4* xp = (const float4*)(xrow + k);
    float4 x0 = xp[0], x1 = xp[1];
    union { short8 s; unsigned int u[4]; } af;
    af.u[0] = cvtpk(x0.x, x0.y);
    af.u[1] = cvtpk(x0.z, x0.w);
    af.u[2] = cvtpk(x1.x, x1.y);
    af.u[3] = cvtpk(x1.z, x1.w);
#pragma unroll
    for (int ct = 0; ct < 4; ++ct) {
      short8 bf = *(const short8*)(vb + (size_t)(ct * 16 + lr) * NN + k);
      acc[ct] = __builtin_amdgcn_mfma_f32_16x16x32_bf16(af.s, bf, acc[ct], 0, 0, 0);
    }
  }
  if (half) {
#pragma unroll
    for (int ct = 0; ct < 4; ++ct)
#pragma unroll
      for (int j = 0; j < 4; ++j)
        red[wq][4 * g + j][ct * 16 + lr] = acc[ct][j];
  }
  __syncthreads();
  if (!half) {
    float* ab = a + ((size_t)b * MM + m0 + wq * 16) * 64;
#pragma unroll
    for (int ct = 0; ct < 4; ++ct)
#pragma unroll
      for (int j = 0; j < 4; ++j)
        ab[(size_t)(4 * g + j) * 64 + ct * 16 + lr] =
            acc[ct][j] + red[wq][4 * g + j][ct * 16 + lr];
  }
}

// a[b][n][r] = sum_m x[b][m][n] * u[b][m][r];  uT = [B,64,M] bf16
// A = x^T staged via XOR-swizzled LDS; K-split 2 across wave halves.
// grid (N/64, B), block 512
__global__ void __launch_bounds__(512, 4)
gemm_xtu(const float* __restrict__ x,
         const unsigned short* __restrict__ uT,
         float* __restrict__ a) {
  __shared__ unsigned short xt[2][64 * 64];
  __shared__ float red[4][16][66];
  int b = blockIdx.y;
  int n0 = blockIdx.x * 64;
  int tid = threadIdx.x;
  int w = tid >> 6, l = tid & 63;
  int lr = l & 15, g = l >> 4;
  int half = w >> 2, wq = w & 3;
  const float* xb = x + (size_t)b * MM * NN + (size_t)(half * (MM / 2)) * NN;
  const unsigned short* ub = uT + (size_t)b * 64 * MM + half * (MM / 2);
  f32x4 acc[4] = {};
  int ht = tid & 255;
  int sn = ht & 63;
  int sm0 = ((ht >> 6) & 3) * 2;
  int nrow = wq * 16 + lr;
  unsigned short* myxt = xt[half];
  for (int k0 = 0; k0 < MM / 2; k0 += 64) {
    __syncthreads();
#pragma unroll
    for (int i = 0; i < 8; ++i) {
      int m = sm0 + i * 8;
      float v0 = xb[(size_t)(k0 + m) * NN + n0 + sn];
      float v1 = xb[(size_t)(k0 + m + 1) * NN + n0 + sn];
      *(unsigned int*)((char*)myxt + (sn * 128 + ((2 * m) ^ ((sn & 7) << 4)))) = cvtpk(v0, v1);
    }
    __syncthreads();
#pragma unroll
    for (int kh = 0; kh < 2; ++kh) {
      int byteoff = nrow * 128 + ((kh * 64 + g * 16) ^ ((lr & 7) << 4));
      short8 af = *(const short8*)((const char*)myxt + byteoff);
      int k = k0 + kh * 32 + 8 * g;
#pragma unroll
      for (int ct = 0; ct < 4; ++ct) {
        short8 bf = *(const short8*)(ub + (size_t)(ct * 16 + lr) * MM + k);
        acc[ct] = __builtin_amdgcn_mfma_f32_16x16x32_bf16(af, bf, acc[ct], 0, 0, 0);
      }
    }
  }
  if (half) {
#pragma unroll
    for (int ct = 0; ct < 4; ++ct)
#pragma unroll
      for (int j = 0; j < 4; ++j)
        red[wq][4 * g + j][ct * 16 + lr] = acc[ct][j];
  }
  __syncthreads();
  if (!half) {
    float* ab = a + ((size_t)b * NN + n0 + wq * 16) * 64;
#pragma unroll
    for (int ct = 0; ct < 4; ++ct)
#pragma unroll
      for (int j = 0; j < 4; ++j)
        ab[(size_t)(4 * g + j) * 64 + ct * 16 + lr] =
            acc[ct][j] + red[wq][4 * g + j][ct * 16 + lr];
  }
}

// Coordinate descent: one wave per row. lane c owns u[c], a[c], g[c].
// g[c] = sum_j u_cur[j]*b[j][c], maintained incrementally.
// Divide hoisted: inv_c = 1/(b[c][c]+l2e); only lane r's quotient is used.
// grid (nrows/4, B), block 256 (4 waves)
__global__ void cd_kernel(const float* __restrict__ u_in,
                          const float* __restrict__ a_ws,
                          const float* __restrict__ bmat,
                          float* __restrict__ u_out,
                          float l1, float l2e, int nrows) {
  __shared__ float bs[4096];
  int b = blockIdx.y;
  int tid = threadIdx.x;
  const float* bsrc = bmat + b * 4096;
  for (int i = tid; i < 4096; i += 256) bs[i] = bsrc[i];
  __syncthreads();
  int w = tid >> 6, c = tid & 63;
  int m = blockIdx.x * 4 + w;
  size_t base = ((size_t)b * nrows + m) * 64;
  float u_c = u_in[base + c];
  float a_c = a_ws[base + c];
  float inv_c = 1.0f / (bs[c * 65] + l2e);
  float g_c = 0.f;
#pragma unroll 16
  for (int j = 0; j < 64; ++j)
    g_c = fmaf(__shfl(u_c, j), bs[j * 64 + c], g_c);
#pragma unroll
  for (int r = 0; r < 64; ++r) {
    float brc = bs[r * 64 + c];
    float num = fmaf(u_c, brc, a_c - g_c);  // lane r: a_r - (g_r - u_r*b_rr)
    float st = copysignf(fmaxf(fabsf(num) - l1, 0.f), num);
    float delta = fmaf(st, inv_c, -u_c);    // lane r's value is the true delta
    delta = __shfl(delta, r);
    if (c == r) u_c += delta;
    g_c = fmaf(delta, brc, g_c);
  }
  u_out[base + c] = u_c;
}

extern "C" void kernel_launch(void* const* d_in, const int* in_sizes, int n_in,
                              void* d_out, int out_size, void* d_ws, size_t ws_size,
                              hipStream_t stream) {
  (void)in_sizes; (void)n_in; (void)out_size; (void)ws_size;
  const float* x = (const float*)d_in[0];
  const float* u = (const float*)d_in[1];
  const float* v = (const float*)d_in[2];
  float* u_out = (float*)d_out;
  float* v_out = u_out + (size_t)BB * MM * 64;

  float* a_ws = (float*)d_ws;                                        // 8.39 MB
  float* b_ws = (float*)((char*)d_ws + (size_t)BB * MM * 64 * 4);    // 256 KB
  unsigned short* tT = (unsigned short*)((char*)b_ws + (size_t)BB * 4096 * 4);

  float l1u = (float)(0.01 * 0.1 * (double)NN);
  float l2u = (float)(0.01 * 0.9 * (double)NN + 1e-16);
  float l1v = (float)(0.01 * 0.1 * (double)MM);
  float l2v = (float)(0.01 * 0.9 * (double)MM + 1e-16);

  // ---- factor 0: update u ----
  hipMemsetAsync(b_ws, 0, (size_t)BB * 4096 * 4, stream);
  transpose_cvt<<<dim3(NN / 64, BB), 256, 0, stream>>>(v, tT, NN);
  gemm_gram<<<dim3(16, BB), 256, 0, stream>>>(tT, b_ws, NN);
  gemm_xv<<<dim3(MM / 64, BB), 512, 0, stream>>>(x, tT, a_ws);
  cd_kernel<<<dim3(MM / 4, BB), 256, 0, stream>>>(u, a_ws, b_ws, u_out, l1u, l2u, MM);

  // ---- factor 1: update v (uses new u) ----
  hipMemsetAsync(b_ws, 0, (size_t)BB * 4096 * 4, stream);
  transpose_cvt<<<dim3(MM / 64, BB), 256, 0, stream>>>(u_out, tT, MM);
  gemm_gram<<<dim3(16, BB), 256, 0, stream>>>(tT, b_ws, MM);
  gemm_xtu<<<dim3(NN / 64, BB), 512, 0, stream>>>(x, tT, a_ws);
  cd_kernel<<<dim3(NN / 4, BB), 256, 0, stream>>>(v, a_ws, b_ws, v_out, l1v, l2v, NN);
}

// Round 4
// 306.302 us; speedup vs baseline: 1.2007x; 1.1410x over previous
//
#include <hip/hip_runtime.h>

typedef __attribute__((ext_vector_type(8))) short short8;
typedef __attribute__((ext_vector_type(4))) float f32x4;

#define BB 16
#define MM 2048
#define NN 2048

static __device__ __forceinline__ unsigned int cvtpk(float lo, float hi) {
  unsigned int r;
  asm("v_cvt_pk_bf16_f32 %0, %1, %2" : "=v"(r) : "v"(lo), "v"(hi));
  return r;
}
static __device__ __forceinline__ float rdlane(float v, int l) {
  return __uint_as_float(__builtin_amdgcn_readlane(__float_as_uint(v), l));
}

// in: [B, nrows, 64] f32 -> out: [B, 64, nrows] bf16
__global__ void transpose_cvt(const float* __restrict__ in,
                              unsigned short* __restrict__ out, int nrows) {
  __shared__ float t[64][65];
  int b = blockIdx.y;
  int n0 = blockIdx.x * 64;
  int tid = threadIdx.x;
  int lane = tid & 63;
  int q = tid >> 6;
  const float* inb = in + ((size_t)b * nrows + n0) * 64;
#pragma unroll
  for (int i = 0; i < 16; ++i) {
    int n = q * 16 + i;
    t[n][lane] = inb[n * 64 + lane];
  }
  __syncthreads();
  unsigned short* outb = out + (size_t)b * 64 * nrows + n0;
  int pr = tid & 31, rq = tid >> 5;
#pragma unroll
  for (int i = 0; i < 8; ++i) {
    int r = rq + 8 * i;
    int n = 2 * pr;
    *(unsigned int*)(outb + (size_t)r * nrows + n) = cvtpk(t[n][r], t[n + 1][r]);
  }
}

// Gram: bmat[b] = T * T^T, T = [64, K] bf16 row-major. No atomics:
// 4 waves split K, LDS reduce. grid (B), block 256.
__global__ void gemm_gram2(const unsigned short* __restrict__ tT,
                           float* __restrict__ bmat, int K) {
  __shared__ float part[4][64][65];
  int b = blockIdx.x;
  int tid = threadIdx.x;
  int w = tid >> 6, l = tid & 63;
  int lr = l & 15, g = l >> 4;
  const unsigned short* vb = tT + (size_t)b * 64 * K;
  int kslice = K >> 2;
  int kbase = w * kslice;
  f32x4 acc[4][4] = {};
  for (int kk = 0; kk < kslice; kk += 32) {
    int k = kbase + kk + 8 * g;
    short8 fr[4];
#pragma unroll
    for (int rt = 0; rt < 4; ++rt)
      fr[rt] = *(const short8*)(vb + (size_t)(rt * 16 + lr) * K + k);
#pragma unroll
    for (int rt = 0; rt < 4; ++rt)
#pragma unroll
      for (int ct = 0; ct < 4; ++ct)
        acc[rt][ct] = __builtin_amdgcn_mfma_f32_16x16x32_bf16(fr[rt], fr[ct], acc[rt][ct], 0, 0, 0);
  }
#pragma unroll
  for (int rt = 0; rt < 4; ++rt)
#pragma unroll
    for (int ct = 0; ct < 4; ++ct)
#pragma unroll
      for (int j = 0; j < 4; ++j)
        part[w][rt * 16 + 4 * g + j][ct * 16 + lr] = acc[rt][ct][j];
  __syncthreads();
  float* bb = bmat + b * 4096;
  for (int i = tid; i < 4096; i += 256) {
    int row = i >> 6, col = i & 63;
    bb[i] = part[0][row][col] + part[1][row][col] + part[2][row][col] + part[3][row][col];
  }
}

// a[b][m][r] = sum_n x[b][m][n] * v[b][n][r];  vT = [B,64,N] bf16
// grid (M/64, B), block 512 = 8 waves: waves 0-3 K-half 0, waves 4-7 K-half 1
__global__ void __launch_bounds__(512, 4)
gemm_xv(const float* __restrict__ x,
        const unsigned short* __restrict__ vT,
        float* __restrict__ a) {
  __shared__ float red[4][16][66];
  int b = blockIdx.y;
  int m0 = blockIdx.x * 64;
  int tid = threadIdx.x;
  int w = tid >> 6, l = tid & 63;
  int lr = l & 15, g = l >> 4;
  int half = w >> 2, wq = w & 3;
  const float* xrow = x + (size_t)b * MM * NN + (size_t)(m0 + wq * 16 + lr) * NN + half * (NN / 2);
  const unsigned short* vb = vT + (size_t)b * 64 * NN + half * (NN / 2);
  f32x4 acc[4] = {};
#pragma unroll 4
  for (int k0 = 0; k0 < NN / 2; k0 += 32) {
    int k = k0 + 8 * g;
    const float4* xp = (const float4*)(xrow + k);
    float4 x0 = xp[0], x1 = xp[1];
    union { short8 s; unsigned int u[4]; } af;
    af.u[0] = cvtpk(x0.x, x0.y);
    af.u[1] = cvtpk(x0.z, x0.w);
    af.u[2] = cvtpk(x1.x, x1.y);
    af.u[3] = cvtpk(x1.z, x1.w);
#pragma unroll
    for (int ct = 0; ct < 4; ++ct) {
      short8 bf = *(const short8*)(vb + (size_t)(ct * 16 + lr) * NN + k);
      acc[ct] = __builtin_amdgcn_mfma_f32_16x16x32_bf16(af.s, bf, acc[ct], 0, 0, 0);
    }
  }
  if (half) {
#pragma unroll
    for (int ct = 0; ct < 4; ++ct)
#pragma unroll
      for (int j = 0; j < 4; ++j)
        red[wq][4 * g + j][ct * 16 + lr] = acc[ct][j];
  }
  __syncthreads();
  if (!half) {
    float* ab = a + ((size_t)b * MM + m0 + wq * 16) * 64;
#pragma unroll
    for (int ct = 0; ct < 4; ++ct)
#pragma unroll
      for (int j = 0; j < 4; ++j)
        ab[(size_t)(4 * g + j) * 64 + ct * 16 + lr] =
            acc[ct][j] + red[wq][4 * g + j][ct * 16 + lr];
  }
}

// a[b][n][r] = sum_m x[b][m][n] * u[b][m][r];  uT = [B,64,M] bf16
// x^T tile staged as f32 via global_load_lds (linear dest, XOR-swizzled
// source at 64B granularity keyed by (row>>3)&1), double-buffered.
// grid (N/64, B), block 512; K-split 2 across wave halves.
__global__ void __launch_bounds__(512, 4)
gemm_xtu(const float* __restrict__ x,
         const unsigned short* __restrict__ uT,
         float* __restrict__ a) {
  __shared__ char smem[65536];  // [half][dbuf] 16KB stage tiles; red aliased after loop
  int b = blockIdx.y;
  int n0 = blockIdx.x * 64;
  int tid = threadIdx.x;
  int w = tid >> 6, l = tid & 63;
  int lr = l & 15, g = l >> 4;
  int half = w >> 2, wq = w & 3;
  int nr = wq * 16 + lr;  // A-row (n within tile)
  const unsigned short* ubh = uT + (size_t)b * 64 * MM + half * 1024;
  const char* xg0 = (const char*)x + (((size_t)b * MM + half * 1024) * NN + n0) * 4;
  f32x4 acc[4] = {};

#define STAGE(DB, CH)                                                                   \
  {                                                                                     \
    const char* xg = xg0 + (size_t)(CH) * 64 * (NN * 4);                                \
    char* lbs = smem + (half * 2 + (DB)) * 16384;                                       \
    _Pragma("unroll")                                                                   \
    for (int i = 0; i < 4; ++i) {                                                       \
      int g4 = wq * 4 + i;                                                              \
      int key = ((g4 >> 1) & 1) << 6;                                                   \
      const char* gp = xg + (size_t)(g4 * 4 + (l >> 4)) * (NN * 4) +                    \
                       (((l & 15) * 16) ^ key);                                         \
      __builtin_amdgcn_global_load_lds(                                                 \
          (const __attribute__((address_space(1))) unsigned int*)gp,                    \
          (__attribute__((address_space(3))) unsigned int*)(lbs + g4 * 1024), 16, 0, 0);\
    }                                                                                   \
  }

  STAGE(0, 0);
  __syncthreads();
  for (int c = 0; c < 16; ++c) {
    int db = c & 1;
    if (c + 1 < 16) STAGE(db ^ 1, c + 1);
    const char* lb = smem + (half * 2 + db) * 16384;
#pragma unroll
    for (int kh = 0; kh < 2; ++kh) {
      float vv[8];
#pragma unroll
      for (int j = 0; j < 8; ++j)
        vv[j] = *(const float*)(lb + (kh * 32 + 8 * g + j) * 256 + ((nr * 4) ^ ((g & 1) << 6)));
      union { short8 s; unsigned int u[4]; } af;
      af.u[0] = cvtpk(vv[0], vv[1]);
      af.u[1] = cvtpk(vv[2], vv[3]);
      af.u[2] = cvtpk(vv[4], vv[5]);
      af.u[3] = cvtpk(vv[6], vv[7]);
      int k = c * 64 + kh * 32 + 8 * g;
#pragma unroll
      for (int ct = 0; ct < 4; ++ct) {
        short8 bf = *(const short8*)(ubh + (size_t)(ct * 16 + lr) * MM + k);
        acc[ct] = __builtin_amdgcn_mfma_f32_16x16x32_bf16(af.s, bf, acc[ct], 0, 0, 0);
      }
    }
    __syncthreads();  // drains vmcnt: stage(c+1) landed; all reads of buf done
  }
#undef STAGE

  float (*red)[16][66] = (float (*)[16][66])smem;  // aliases dead stage buffers
  if (half) {
#pragma unroll
    for (int ct = 0; ct < 4; ++ct)
#pragma unroll
      for (int j = 0; j < 4; ++j)
        red[wq][4 * g + j][ct * 16 + lr] = acc[ct][j];
  }
  __syncthreads();
  if (!half) {
    float* ab = a + ((size_t)b * NN + n0 + wq * 16) * 64;
#pragma unroll
    for (int ct = 0; ct < 4; ++ct)
#pragma unroll
      for (int j = 0; j < 4; ++j)
        ab[(size_t)(4 * g + j) * 64 + ct * 16 + lr] =
            acc[ct][j] + red[wq][4 * g + j][ct * 16 + lr];
  }
}

// Coordinate descent: one wave per row, lane c owns column c.
// amg = a_c - sum_j u_cur[j] b[j][c] maintained incrementally; u never
// mutated in-loop (only lane r's num matters at iter r, pre-update value).
// grid (nrows/4, B), block 256
__global__ void cd_kernel(const float* __restrict__ u_in,
                          const float* __restrict__ a_ws,
                          const float* __restrict__ bmat,
                          float* __restrict__ u_out,
                          float l1, float l2e, int nrows) {
  __shared__ float bs[4096];
  int b = blockIdx.y;
  int tid = threadIdx.x;
  const float4* bsrc = (const float4*)(bmat + b * 4096);
  float4* bd = (float4*)bs;
  for (int i = tid; i < 1024; i += 256) bd[i] = bsrc[i];
  __syncthreads();
  int w = tid >> 6, c = tid & 63;
  int m = blockIdx.x * 4 + w;
  size_t base = ((size_t)b * nrows + m) * 64;
  float u_c = u_in[base + c];
  float a_c = a_ws[base + c];
  float inv_c = 1.0f / (bs[c * 65] + l2e);
  float g_c = 0.f;
#pragma unroll
  for (int j = 0; j < 64; ++j)
    g_c = fmaf(rdlane(u_c, j), bs[j * 64 + c], g_c);
  float amg = a_c - g_c;
  float u_fin = u_c;
#pragma unroll
  for (int r = 0; r < 64; ++r) {
    float brc = bs[r * 64 + c];
    float num = fmaf(u_c, brc, amg);
    float cl = fminf(fmaxf(num, -l1), l1);   // v_med3
    float stinv = (num - cl) * inv_c;
    float du_v = stinv - u_c;
    float s_du = rdlane(du_v, r);
    float s_unew = rdlane(stinv, r);
    if (c == r) u_fin = s_unew;              // v_cndmask, off the serial chain
    amg = fmaf(-s_du, brc, amg);
  }
  u_out[base + c] = u_fin;
}

extern "C" void kernel_launch(void* const* d_in, const int* in_sizes, int n_in,
                              void* d_out, int out_size, void* d_ws, size_t ws_size,
                              hipStream_t stream) {
  (void)in_sizes; (void)n_in; (void)out_size; (void)ws_size;
  const float* x = (const float*)d_in[0];
  const float* u = (const float*)d_in[1];
  const float* v = (const float*)d_in[2];
  float* u_out = (float*)d_out;
  float* v_out = u_out + (size_t)BB * MM * 64;

  float* a_ws = (float*)d_ws;                                        // 8.39 MB
  float* b_ws = (float*)((char*)d_ws + (size_t)BB * MM * 64 * 4);    // 256 KB
  unsigned short* tT = (unsigned short*)((char*)b_ws + (size_t)BB * 4096 * 4);

  float l1u = (float)(0.01 * 0.1 * (double)NN);
  float l2u = (float)(0.01 * 0.9 * (double)NN + 1e-16);
  float l1v = (float)(0.01 * 0.1 * (double)MM);
  float l2v = (float)(0.01 * 0.9 * (double)MM + 1e-16);

  // ---- factor 0: update u ----
  transpose_cvt<<<dim3(NN / 64, BB), 256, 0, stream>>>(v, tT, NN);
  gemm_gram2<<<dim3(BB), 256, 0, stream>>>(tT, b_ws, NN);
  gemm_xv<<<dim3(MM / 64, BB), 512, 0, stream>>>(x, tT, a_ws);
  cd_kernel<<<dim3(MM / 4, BB), 256, 0, stream>>>(u, a_ws, b_ws, u_out, l1u, l2u, MM);

  // ---- factor 1: update v (uses new u) ----
  transpose_cvt<<<dim3(MM / 64, BB), 256, 0, stream>>>(u_out, tT, MM);
  gemm_gram2<<<dim3(BB), 256, 0, stream>>>(tT, b_ws, MM);
  gemm_xtu<<<dim3(NN / 64, BB), 512, 0, stream>>>(x, tT, a_ws);
  cd_kernel<<<dim3(NN / 4, BB), 256, 0, stream>>>(v, a_ws, b_ws, v_out, l1v, l2v, NN);
}

// Round 5
// 282.303 us; speedup vs baseline: 1.3027x; 1.0850x over previous
//
#include <hip/hip_runtime.h>

typedef __attribute__((ext_vector_type(8))) short short8;
typedef __attribute__((ext_vector_type(4))) float f32x4;

#define BB 16
#define MM 2048
#define NN 2048

static __device__ __forceinline__ unsigned int cvtpk(float lo, float hi) {
  unsigned int r;
  asm("v_cvt_pk_bf16_f32 %0, %1, %2" : "=v"(r) : "v"(lo), "v"(hi));
  return r;
}
static __device__ __forceinline__ float rdlane(float v, int l) {
  return __uint_as_float(__builtin_amdgcn_readlane(__float_as_uint(v), l));
}

// in: [B, nrows, 64] f32 -> out: [B, 64, nrows] bf16
__global__ void transpose_cvt(const float* __restrict__ in,
                              unsigned short* __restrict__ out, int nrows) {
  __shared__ float t[64][65];
  int b = blockIdx.y;
  int n0 = blockIdx.x * 64;
  int tid = threadIdx.x;
  int lane = tid & 63;
  int q = tid >> 6;
  const float* inb = in + ((size_t)b * nrows + n0) * 64;
#pragma unroll
  for (int i = 0; i < 16; ++i) {
    int n = q * 16 + i;
    t[n][lane] = inb[n * 64 + lane];
  }
  __syncthreads();
  unsigned short* outb = out + (size_t)b * 64 * nrows + n0;
  int pr = tid & 31, rq = tid >> 5;
#pragma unroll
  for (int i = 0; i < 8; ++i) {
    int r = rq + 8 * i;
    int n = 2 * pr;
    *(unsigned int*)(outb + (size_t)r * nrows + n) = cvtpk(t[n][r], t[n + 1][r]);
  }
}

// Gram: bmat[b] = T * T^T, T = [64, K] bf16 row-major. No atomics:
// 4 waves split K, LDS reduce. grid (B), block 256.
__global__ void gemm_gram2(const unsigned short* __restrict__ tT,
                           float* __restrict__ bmat, int K) {
  __shared__ float part[4][64][65];
  int b = blockIdx.x;
  int tid = threadIdx.x;
  int w = tid >> 6, l = tid & 63;
  int lr = l & 15, g = l >> 4;
  const unsigned short* vb = tT + (size_t)b * 64 * K;
  int kslice = K >> 2;
  int kbase = w * kslice;
  f32x4 acc[4][4] = {};
  for (int kk = 0; kk < kslice; kk += 32) {
    int k = kbase + kk + 8 * g;
    short8 fr[4];
#pragma unroll
    for (int rt = 0; rt < 4; ++rt)
      fr[rt] = *(const short8*)(vb + (size_t)(rt * 16 + lr) * K + k);
#pragma unroll
    for (int rt = 0; rt < 4; ++rt)
#pragma unroll
      for (int ct = 0; ct < 4; ++ct)
        acc[rt][ct] = __builtin_amdgcn_mfma_f32_16x16x32_bf16(fr[rt], fr[ct], acc[rt][ct], 0, 0, 0);
  }
#pragma unroll
  for (int rt = 0; rt < 4; ++rt)
#pragma unroll
    for (int ct = 0; ct < 4; ++ct)
#pragma unroll
      for (int j = 0; j < 4; ++j)
        part[w][rt * 16 + 4 * g + j][ct * 16 + lr] = acc[rt][ct][j];
  __syncthreads();
  float* bb = bmat + b * 4096;
  for (int i = tid; i < 4096; i += 256) {
    int row = i >> 6, col = i & 63;
    bb[i] = part[0][row][col] + part[1][row][col] + part[2][row][col] + part[3][row][col];
  }
}

// a[b][m][r] = sum_n x[b][m][n] * v[b][n][r];  vT = [B,64,N] bf16
// grid (M/64, B), block 512 = 8 waves: waves 0-3 K-half 0, waves 4-7 K-half 1
__global__ void __launch_bounds__(512, 4)
gemm_xv(const float* __restrict__ x,
        const unsigned short* __restrict__ vT,
        float* __restrict__ a) {
  __shared__ float red[4][16][66];
  int b = blockIdx.y;
  int m0 = blockIdx.x * 64;
  int tid = threadIdx.x;
  int w = tid >> 6, l = tid & 63;
  int lr = l & 15, g = l >> 4;
  int half = w >> 2, wq = w & 3;
  const float* xrow = x + (size_t)b * MM * NN + (size_t)(m0 + wq * 16 + lr) * NN + half * (NN / 2);
  const unsigned short* vb = vT + (size_t)b * 64 * NN + half * (NN / 2);
  f32x4 acc[4] = {};
#pragma unroll 4
  for (int k0 = 0; k0 < NN / 2; k0 += 32) {
    int k = k0 + 8 * g;
    const float4* xp = (const float4*)(xrow + k);
    float4 x0 = xp[0], x1 = xp[1];
    union { short8 s; unsigned int u[4]; } af;
    af.u[0] = cvtpk(x0.x, x0.y);
    af.u[1] = cvtpk(x0.z, x0.w);
    af.u[2] = cvtpk(x1.x, x1.y);
    af.u[3] = cvtpk(x1.z, x1.w);
#pragma unroll
    for (int ct = 0; ct < 4; ++ct) {
      short8 bf = *(const short8*)(vb + (size_t)(ct * 16 + lr) * NN + k);
      acc[ct] = __builtin_amdgcn_mfma_f32_16x16x32_bf16(af.s, bf, acc[ct], 0, 0, 0);
    }
  }
  if (half) {
#pragma unroll
    for (int ct = 0; ct < 4; ++ct)
#pragma unroll
      for (int j = 0; j < 4; ++j)
        red[wq][4 * g + j][ct * 16 + lr] = acc[ct][j];
  }
  __syncthreads();
  if (!half) {
    float* ab = a + ((size_t)b * MM + m0 + wq * 16) * 64;
#pragma unroll
    for (int ct = 0; ct < 4; ++ct)
#pragma unroll
      for (int j = 0; j < 4; ++j)
        ab[(size_t)(4 * g + j) * 64 + ct * 16 + lr] =
            acc[ct][j] + red[wq][4 * g + j][ct * 16 + lr];
  }
}

// a[b][n][r] = sum_m x[b][m][n] * u[b][m][r];  uT = [B,64,M] bf16
// x^T tile staged as f32 via global_load_lds, double-buffered.
// BATCH ORDER REVERSED: x == L3 size; xv leaves the tail of x freshest,
// so the second pass reads batches in reverse for L3 hits.
// grid (N/64, B), block 512; K-split 2 across wave halves.
__global__ void __launch_bounds__(512, 4)
gemm_xtu(const float* __restrict__ x,
         const unsigned short* __restrict__ uT,
         float* __restrict__ a) {
  __shared__ char smem[65536];  // [half][dbuf] 16KB stage tiles; red aliased after loop
  int b = (BB - 1) - blockIdx.y;   // reverse-order second pass over x
  int n0 = blockIdx.x * 64;
  int tid = threadIdx.x;
  int w = tid >> 6, l = tid & 63;
  int lr = l & 15, g = l >> 4;
  int half = w >> 2, wq = w & 3;
  int nr = wq * 16 + lr;  // A-row (n within tile)
  const unsigned short* ubh = uT + (size_t)b * 64 * MM + half * 1024;
  const char* xg0 = (const char*)x + (((size_t)b * MM + half * 1024) * NN + n0) * 4;
  f32x4 acc[4] = {};

#define STAGE(DB, CH)                                                                   \
  {                                                                                     \
    const char* xg = xg0 + (size_t)(CH) * 64 * (NN * 4);                                \
    char* lbs = smem + (half * 2 + (DB)) * 16384;                                       \
    _Pragma("unroll")                                                                   \
    for (int i = 0; i < 4; ++i) {                                                       \
      int g4 = wq * 4 + i;                                                              \
      int key = ((g4 >> 1) & 1) << 6;                                                   \
      const char* gp = xg + (size_t)(g4 * 4 + (l >> 4)) * (NN * 4) +                    \
                       (((l & 15) * 16) ^ key);                                         \
      __builtin_amdgcn_global_load_lds(                                                 \
          (const __attribute__((address_space(1))) unsigned int*)gp,                    \
          (__attribute__((address_space(3))) unsigned int*)(lbs + g4 * 1024), 16, 0, 0);\
    }                                                                                   \
  }

  STAGE(0, 0);
  __syncthreads();
  for (int c = 0; c < 16; ++c) {
    int db = c & 1;
    if (c + 1 < 16) STAGE(db ^ 1, c + 1);
    const char* lb = smem + (half * 2 + db) * 16384;
#pragma unroll
    for (int kh = 0; kh < 2; ++kh) {
      float vv[8];
#pragma unroll
      for (int j = 0; j < 8; ++j)
        vv[j] = *(const float*)(lb + (kh * 32 + 8 * g + j) * 256 + ((nr * 4) ^ ((g & 1) << 6)));
      union { short8 s; unsigned int u[4]; } af;
      af.u[0] = cvtpk(vv[0], vv[1]);
      af.u[1] = cvtpk(vv[2], vv[3]);
      af.u[2] = cvtpk(vv[4], vv[5]);
      af.u[3] = cvtpk(vv[6], vv[7]);
      int k = c * 64 + kh * 32 + 8 * g;
#pragma unroll
      for (int ct = 0; ct < 4; ++ct) {
        short8 bf = *(const short8*)(ubh + (size_t)(ct * 16 + lr) * MM + k);
        acc[ct] = __builtin_amdgcn_mfma_f32_16x16x32_bf16(af.s, bf, acc[ct], 0, 0, 0);
      }
    }
    __syncthreads();  // drains vmcnt: stage(c+1) landed; all reads of buf done
  }
#undef STAGE

  float (*red)[16][66] = (float (*)[16][66])smem;  // aliases dead stage buffers
  if (half) {
#pragma unroll
    for (int ct = 0; ct < 4; ++ct)
#pragma unroll
      for (int j = 0; j < 4; ++j)
        red[wq][4 * g + j][ct * 16 + lr] = acc[ct][j];
  }
  __syncthreads();
  if (!half) {
    float* ab = a + ((size_t)b * NN + n0 + wq * 16) * 64;
#pragma unroll
    for (int ct = 0; ct < 4; ++ct)
#pragma unroll
      for (int j = 0; j < 4; ++j)
        ab[(size_t)(4 * g + j) * 64 + ct * 16 + lr] =
            acc[ct][j] + red[wq][4 * g + j][ct * 16 + lr];
  }
}

// Coordinate descent: one wave per row, lane c owns column c.
// amg = a_c - sum_j u_cur[j] b[j][c] maintained incrementally; u never
// mutated in-loop. Lane-r result committed via v_writelane (r is a literal
// in the unrolled loop) instead of cmp+cndmask.
// grid (nrows/4, B), block 256
__global__ void cd_kernel(const float* __restrict__ u_in,
                          const float* __restrict__ a_ws,
                          const float* __restrict__ bmat,
                          float* __restrict__ u_out,
                          float l1, float l2e, int nrows) {
  __shared__ float bs[4096];
  int b = blockIdx.y;
  int tid = threadIdx.x;
  const float4* bsrc = (const float4*)(bmat + b * 4096);
  float4* bd = (float4*)bs;
  for (int i = tid; i < 1024; i += 256) bd[i] = bsrc[i];
  __syncthreads();
  int w = tid >> 6, c = tid & 63;
  int m = blockIdx.x * 4 + w;
  size_t base = ((size_t)b * nrows + m) * 64;
  float u_c = u_in[base + c];
  float a_c = a_ws[base + c];
  float inv_c = 1.0f / (bs[c * 65] + l2e);
  float g_c = 0.f;
#pragma unroll
  for (int j = 0; j < 64; ++j)
    g_c = fmaf(rdlane(u_c, j), bs[j * 64 + c], g_c);
  float amg = a_c - g_c;
  float u_fin = u_c;
#pragma unroll
  for (int r = 0; r < 64; ++r) {
    float brc = bs[r * 64 + c];
    float num = fmaf(u_c, brc, amg);
    float cl = fminf(fmaxf(num, -l1), l1);   // v_med3
    float stinv = (num - cl) * inv_c;
    float du_v = stinv - u_c;
    float s_du = rdlane(du_v, r);
    float s_unew = rdlane(stinv, r);
    // u_fin[lane r] = s_unew  (writelane: SGPR src, literal lane)
    asm("v_writelane_b32 %0, %1, %2" : "+v"(u_fin) : "s"(s_unew), "i"(r));
    amg = fmaf(-s_du, brc, amg);
  }
  u_out[base + c] = u_fin;
}

extern "C" void kernel_launch(void* const* d_in, const int* in_sizes, int n_in,
                              void* d_out, int out_size, void* d_ws, size_t ws_size,
                              hipStream_t stream) {
  (void)in_sizes; (void)n_in; (void)out_size; (void)ws_size;
  const float* x = (const float*)d_in[0];
  const float* u = (const float*)d_in[1];
  const float* v = (const float*)d_in[2];
  float* u_out = (float*)d_out;
  float* v_out = u_out + (size_t)BB * MM * 64;

  float* a_ws = (float*)d_ws;                                        // 8.39 MB
  float* b_ws = (float*)((char*)d_ws + (size_t)BB * MM * 64 * 4);    // 256 KB
  unsigned short* tT = (unsigned short*)((char*)b_ws + (size_t)BB * 4096 * 4);

  float l1u = (float)(0.01 * 0.1 * (double)NN);
  float l2u = (float)(0.01 * 0.9 * (double)NN + 1e-16);
  float l1v = (float)(0.01 * 0.1 * (double)MM);
  float l2v = (float)(0.01 * 0.9 * (double)MM + 1e-16);

  // ---- factor 0: update u ----
  transpose_cvt<<<dim3(NN / 64, BB), 256, 0, stream>>>(v, tT, NN);
  gemm_gram2<<<dim3(BB), 256, 0, stream>>>(tT, b_ws, NN);
  gemm_xv<<<dim3(MM / 64, BB), 512, 0, stream>>>(x, tT, a_ws);
  cd_kernel<<<dim3(MM / 4, BB), 256, 0, stream>>>(u, a_ws, b_ws, u_out, l1u, l2u, MM);

  // ---- factor 1: update v (uses new u) ----
  transpose_cvt<<<dim3(MM / 64, BB), 256, 0, stream>>>(u_out, tT, MM);
  gemm_gram2<<<dim3(BB), 256, 0, stream>>>(tT, b_ws, MM);
  gemm_xtu<<<dim3(NN / 64, BB), 512, 0, stream>>>(x, tT, a_ws);
  cd_kernel<<<dim3(NN / 4, BB), 256, 0, stream>>>(v, a_ws, b_ws, v_out, l1v, l2v, NN);
}

// Round 6
// 262.687 us; speedup vs baseline: 1.4000x; 1.0747x over previous
//
#include <hip/hip_runtime.h>

typedef __attribute__((ext_vector_type(8))) short short8;
typedef __attribute__((ext_vector_type(4))) float f32x4;

#define BB 16
#define MM 2048
#define NN 2048

static __device__ __forceinline__ unsigned int cvtpk(float lo, float hi) {
  unsigned int r;
  asm("v_cvt_pk_bf16_f32 %0, %1, %2" : "=v"(r) : "v"(lo), "v"(hi));
  return r;
}
static __device__ __forceinline__ float rdlane(float v, int l) {
  return __uint_as_float(__builtin_amdgcn_readlane(__float_as_uint(v), l));
}

// in: [B, nrows, 64] f32 -> out: [B, 64, nrows] bf16
__global__ void transpose_cvt(const float* __restrict__ in,
                              unsigned short* __restrict__ out, int nrows) {
  __shared__ float t[64][65];
  int b = blockIdx.y;
  int n0 = blockIdx.x * 64;
  int tid = threadIdx.x;
  int lane = tid & 63;
  int q = tid >> 6;
  const float* inb = in + ((size_t)b * nrows + n0) * 64;
#pragma unroll
  for (int i = 0; i < 16; ++i) {
    int n = q * 16 + i;
    t[n][lane] = inb[n * 64 + lane];
  }
  __syncthreads();
  unsigned short* outb = out + (size_t)b * 64 * nrows + n0;
  int pr = tid & 31, rq = tid >> 5;
#pragma unroll
  for (int i = 0; i < 8; ++i) {
    int r = rq + 8 * i;
    int n = 2 * pr;
    *(unsigned int*)(outb + (size_t)r * nrows + n) = cvtpk(t[n][r], t[n + 1][r]);
  }
}

// Gram: bmat[b] = T * T^T, T = [64, K] bf16 row-major. No atomics:
// 4 waves split K, LDS reduce. grid (B), block 256.
__global__ void gemm_gram2(const unsigned short* __restrict__ tT,
                           float* __restrict__ bmat, int K) {
  __shared__ float part[4][64][65];
  int b = blockIdx.x;
  int tid = threadIdx.x;
  int w = tid >> 6, l = tid & 63;
  int lr = l & 15, g = l >> 4;
  const unsigned short* vb = tT + (size_t)b * 64 * K;
  int kslice = K >> 2;
  int kbase = w * kslice;
  f32x4 acc[4][4] = {};
  for (int kk = 0; kk < kslice; kk += 32) {
    int k = kbase + kk + 8 * g;
    short8 fr[4];
#pragma unroll
    for (int rt = 0; rt < 4; ++rt)
      fr[rt] = *(const short8*)(vb + (size_t)(rt * 16 + lr) * K + k);
#pragma unroll
    for (int rt = 0; rt < 4; ++rt)
#pragma unroll
      for (int ct = 0; ct < 4; ++ct)
        acc[rt][ct] = __builtin_amdgcn_mfma_f32_16x16x32_bf16(fr[rt], fr[ct], acc[rt][ct], 0, 0, 0);
  }
#pragma unroll
  for (int rt = 0; rt < 4; ++rt)
#pragma unroll
    for (int ct = 0; ct < 4; ++ct)
#pragma unroll
      for (int j = 0; j < 4; ++j)
        part[w][rt * 16 + 4 * g + j][ct * 16 + lr] = acc[rt][ct][j];
  __syncthreads();
  float* bb = bmat + b * 4096;
  for (int i = tid; i < 4096; i += 256) {
    int row = i >> 6, col = i & 63;
    bb[i] = part[0][row][col] + part[1][row][col] + part[2][row][col] + part[3][row][col];
  }
}

// a[b][m][r] = sum_n x[b][m][n] * v[b][n][r];  vT = [B,64,N] bf16
// x rows DMA-staged via global_load_lds: [128 m][64 n] f32 tile (32 KB),
// double-buffered. Source pre-swizzled (16B slot ^= row&7), read applies
// the same XOR -> structural-optimal b128 reads. No K-split.
// grid (M/128, B), block 512 (8 waves; wave w owns rows w*16..+15).
__global__ void __launch_bounds__(512, 2)
gemm_xv(const float* __restrict__ x,
        const unsigned short* __restrict__ vT,
        float* __restrict__ a) {
  __shared__ char smem[65536];  // 2 x 32 KB stage buffers
  int b = blockIdx.y;
  int m0 = blockIdx.x * 128;
  int tid = threadIdx.x;
  int w = tid >> 6, l = tid & 63;
  int lr = l & 15, g = l >> 4;
  const unsigned short* vb = vT + (size_t)b * 64 * NN;
  const char* xg0 = (const char*)x + ((size_t)b * MM + m0) * (size_t)(NN * 4);
  f32x4 acc[4] = {};
  int rowb = (w * 16 + lr) * 256;  // this lane's A-row base in the tile
  int key = lr & 7;                // read-side swizzle key (= row&7)

  // Stage chunk CH (64 n-cols for all 128 rows) into buffer DB.
  // Instr s covers rows s*4..s*4+3; HW dest = base + lane*16, so lane l is
  // row s*4+(l>>4), physical slot l&15. Source slot = physical ^ (row&7).
#define XVSTAGE(DB, CH)                                                         \
  {                                                                             \
    char* lbs = (char*)smem + (DB)*32768;                                       \
    _Pragma("unroll")                                                           \
    for (int i = 0; i < 4; ++i) {                                               \
      int s = w * 4 + i;                                                        \
      int lg = ((l & 15) ^ ((s & 1) * 4 + (l >> 4))) * 16;                      \
      const char* gp = xg0 + (size_t)(s * 4 + (l >> 4)) * (NN * 4) +            \
                       (CH)*256 + lg;                                           \
      __builtin_amdgcn_global_load_lds(                                         \
          (const __attribute__((address_space(1))) unsigned int*)gp,            \
          (__attribute__((address_space(3))) unsigned int*)(lbs + s * 1024),    \
          16, 0, 0);                                                            \
    }                                                                           \
  }

  XVSTAGE(0, 0);
  __syncthreads();
  for (int c = 0; c < 32; ++c) {
    int db = c & 1;
    if (c + 1 < 32) XVSTAGE(db ^ 1, c + 1);
    const char* lb = (const char*)smem + db * 32768 + rowb;
#pragma unroll
    for (int kh = 0; kh < 2; ++kh) {
      f32x4 lo = *(const f32x4*)(lb + ((kh * 8 + 2 * g + 0) ^ key) * 16);
      f32x4 hi = *(const f32x4*)(lb + ((kh * 8 + 2 * g + 1) ^ key) * 16);
      union { short8 s; unsigned int u[4]; } af;
      af.u[0] = cvtpk(lo[0], lo[1]);
      af.u[1] = cvtpk(lo[2], lo[3]);
      af.u[2] = cvtpk(hi[0], hi[1]);
      af.u[3] = cvtpk(hi[2], hi[3]);
      int k = c * 64 + kh * 32 + 8 * g;
#pragma unroll
      for (int ct = 0; ct < 4; ++ct) {
        short8 bf = *(const short8*)(vb + (size_t)(ct * 16 + lr) * NN + k);
        acc[ct] = __builtin_amdgcn_mfma_f32_16x16x32_bf16(af.s, bf, acc[ct], 0, 0, 0);
      }
    }
    __syncthreads();  // drains vmcnt: stage(c+1) landed; all reads of db done
  }
#undef XVSTAGE

  float* ab = a + ((size_t)b * MM + m0 + w * 16) * 64;
#pragma unroll
  for (int ct = 0; ct < 4; ++ct)
#pragma unroll
    for (int j = 0; j < 4; ++j)
      ab[(size_t)(4 * g + j) * 64 + ct * 16 + lr] = acc[ct][j];
}

// a[b][n][r] = sum_m x[b][m][n] * u[b][m][r];  uT = [B,64,M] bf16
// x^T tile staged as f32 via global_load_lds, double-buffered.
// BATCH ORDER REVERSED: x == L3 size; xv leaves the tail of x freshest,
// so the second pass reads batches in reverse for L3 hits.
// grid (N/64, B), block 512; K-split 2 across wave halves.
__global__ void __launch_bounds__(512, 4)
gemm_xtu(const float* __restrict__ x,
         const unsigned short* __restrict__ uT,
         float* __restrict__ a) {
  __shared__ char smem[65536];  // [half][dbuf] 16KB stage tiles; red aliased after loop
  int b = (BB - 1) - blockIdx.y;   // reverse-order second pass over x
  int n0 = blockIdx.x * 64;
  int tid = threadIdx.x;
  int w = tid >> 6, l = tid & 63;
  int lr = l & 15, g = l >> 4;
  int half = w >> 2, wq = w & 3;
  int nr = wq * 16 + lr;  // A-row (n within tile)
  const unsigned short* ubh = uT + (size_t)b * 64 * MM + half * 1024;
  const char* xg0 = (const char*)x + (((size_t)b * MM + half * 1024) * NN + n0) * 4;
  f32x4 acc[4] = {};

#define STAGE(DB, CH)                                                                   \
  {                                                                                     \
    const char* xg = xg0 + (size_t)(CH) * 64 * (NN * 4);                                \
    char* lbs = smem + (half * 2 + (DB)) * 16384;                                       \
    _Pragma("unroll")                                                                   \
    for (int i = 0; i < 4; ++i) {                                                       \
      int g4 = wq * 4 + i;                                                              \
      int key = ((g4 >> 1) & 1) << 6;                                                   \
      const char* gp = xg + (size_t)(g4 * 4 + (l >> 4)) * (NN * 4) +                    \
                       (((l & 15) * 16) ^ key);                                         \
      __builtin_amdgcn_global_load_lds(                                                 \
          (const __attribute__((address_space(1))) unsigned int*)gp,                    \
          (__attribute__((address_space(3))) unsigned int*)(lbs + g4 * 1024), 16, 0, 0);\
    }                                                                                   \
  }

  STAGE(0, 0);
  __syncthreads();
  for (int c = 0; c < 16; ++c) {
    int db = c & 1;
    if (c + 1 < 16) STAGE(db ^ 1, c + 1);
    const char* lb = smem + (half * 2 + db) * 16384;
#pragma unroll
    for (int kh = 0; kh < 2; ++kh) {
      float vv[8];
#pragma unroll
      for (int j = 0; j < 8; ++j)
        vv[j] = *(const float*)(lb + (kh * 32 + 8 * g + j) * 256 + ((nr * 4) ^ ((g & 1) << 6)));
      union { short8 s; unsigned int u[4]; } af;
      af.u[0] = cvtpk(vv[0], vv[1]);
      af.u[1] = cvtpk(vv[2], vv[3]);
      af.u[2] = cvtpk(vv[4], vv[5]);
      af.u[3] = cvtpk(vv[6], vv[7]);
      int k = c * 64 + kh * 32 + 8 * g;
#pragma unroll
      for (int ct = 0; ct < 4; ++ct) {
        short8 bf = *(const short8*)(ubh + (size_t)(ct * 16 + lr) * MM + k);
        acc[ct] = __builtin_amdgcn_mfma_f32_16x16x32_bf16(af.s, bf, acc[ct], 0, 0, 0);
      }
    }
    __syncthreads();  // drains vmcnt: stage(c+1) landed; all reads of buf done
  }
#undef STAGE

  float (*red)[16][66] = (float (*)[16][66])smem;  // aliases dead stage buffers
  if (half) {
#pragma unroll
    for (int ct = 0; ct < 4; ++ct)
#pragma unroll
      for (int j = 0; j < 4; ++j)
        red[wq][4 * g + j][ct * 16 + lr] = acc[ct][j];
  }
  __syncthreads();
  if (!half) {
    float* ab = a + ((size_t)b * NN + n0 + wq * 16) * 64;
#pragma unroll
    for (int ct = 0; ct < 4; ++ct)
#pragma unroll
      for (int j = 0; j < 4; ++j)
        ab[(size_t)(4 * g + j) * 64 + ct * 16 + lr] =
            acc[ct][j] + red[wq][4 * g + j][ct * 16 + lr];
  }
}

// Coordinate descent: one wave per row, lane c owns column c.
// amg = a_c - sum_j u_cur[j] b[j][c] maintained incrementally; u never
// mutated in-loop. Lane-r result committed via v_writelane (r is a literal
// in the unrolled loop) instead of cmp+cndmask.
// grid (nrows/4, B), block 256
__global__ void cd_kernel(const float* __restrict__ u_in,
                          const float* __restrict__ a_ws,
                          const float* __restrict__ bmat,
                          float* __restrict__ u_out,
                          float l1, float l2e, int nrows) {
  __shared__ float bs[4096];
  int b = blockIdx.y;
  int tid = threadIdx.x;
  const float4* bsrc = (const float4*)(bmat + b * 4096);
  float4* bd = (float4*)bs;
  for (int i = tid; i < 1024; i += 256) bd[i] = bsrc[i];
  __syncthreads();
  int w = tid >> 6, c = tid & 63;
  int m = blockIdx.x * 4 + w;
  size_t base = ((size_t)b * nrows + m) * 64;
  float u_c = u_in[base + c];
  float a_c = a_ws[base + c];
  float inv_c = 1.0f / (bs[c * 65] + l2e);
  float g_c = 0.f;
#pragma unroll
  for (int j = 0; j < 64; ++j)
    g_c = fmaf(rdlane(u_c, j), bs[j * 64 + c], g_c);
  float amg = a_c - g_c;
  float u_fin = u_c;
#pragma unroll
  for (int r = 0; r < 64; ++r) {
    float brc = bs[r * 64 + c];
    float num = fmaf(u_c, brc, amg);
    float cl = fminf(fmaxf(num, -l1), l1);   // v_med3
    float stinv = (num - cl) * inv_c;
    float du_v = stinv - u_c;
    float s_du = rdlane(du_v, r);
    float s_unew = rdlane(stinv, r);
    // u_fin[lane r] = s_unew  (writelane: SGPR src, literal lane)
    asm("v_writelane_b32 %0, %1, %2" : "+v"(u_fin) : "s"(s_unew), "i"(r));
    amg = fmaf(-s_du, brc, amg);
  }
  u_out[base + c] = u_fin;
}

extern "C" void kernel_launch(void* const* d_in, const int* in_sizes, int n_in,
                              void* d_out, int out_size, void* d_ws, size_t ws_size,
                              hipStream_t stream) {
  (void)in_sizes; (void)n_in; (void)out_size; (void)ws_size;
  const float* x = (const float*)d_in[0];
  const float* u = (const float*)d_in[1];
  const float* v = (const float*)d_in[2];
  float* u_out = (float*)d_out;
  float* v_out = u_out + (size_t)BB * MM * 64;

  float* a_ws = (float*)d_ws;                                        // 8.39 MB
  float* b_ws = (float*)((char*)d_ws + (size_t)BB * MM * 64 * 4);    // 256 KB
  unsigned short* tT = (unsigned short*)((char*)b_ws + (size_t)BB * 4096 * 4);

  float l1u = (float)(0.01 * 0.1 * (double)NN);
  float l2u = (float)(0.01 * 0.9 * (double)NN + 1e-16);
  float l1v = (float)(0.01 * 0.1 * (double)MM);
  float l2v = (float)(0.01 * 0.9 * (double)MM + 1e-16);

  // ---- factor 0: update u ----
  transpose_cvt<<<dim3(NN / 64, BB), 256, 0, stream>>>(v, tT, NN);
  gemm_gram2<<<dim3(BB), 256, 0, stream>>>(tT, b_ws, NN);
  gemm_xv<<<dim3(MM / 128, BB), 512, 0, stream>>>(x, tT, a_ws);
  cd_kernel<<<dim3(MM / 4, BB), 256, 0, stream>>>(u, a_ws, b_ws, u_out, l1u, l2u, MM);

  // ---- factor 1: update v (uses new u) ----
  transpose_cvt<<<dim3(MM / 64, BB), 256, 0, stream>>>(u_out, tT, MM);
  gemm_gram2<<<dim3(BB), 256, 0, stream>>>(tT, b_ws, MM);
  gemm_xtu<<<dim3(NN / 64, BB), 512, 0, stream>>>(x, tT, a_ws);
  cd_kernel<<<dim3(NN / 4, BB), 256, 0, stream>>>(v, a_ws, b_ws, v_out, l1v, l2v, NN);
}

// Round 7
// 259.648 us; speedup vs baseline: 1.4164x; 1.0117x over previous
//
#include <hip/hip_runtime.h>

typedef __attribute__((ext_vector_type(8))) short short8;
typedef __attribute__((ext_vector_type(4))) float f32x4;

#define BB 16
#define MM 2048
#define NN 2048

static __device__ __forceinline__ unsigned int cvtpk(float lo, float hi) {
  unsigned int r;
  asm("v_cvt_pk_bf16_f32 %0, %1, %2" : "=v"(r) : "v"(lo), "v"(hi));
  return r;
}
static __device__ __forceinline__ float rdlane(float v, int l) {
  return __uint_as_float(__builtin_amdgcn_readlane(__float_as_uint(v), l));
}

// in: [B, nrows, 64] f32 -> out: [B, 64, nrows] bf16
__global__ void transpose_cvt(const float* __restrict__ in,
                              unsigned short* __restrict__ out, int nrows) {
  __shared__ float t[64][65];
  int b = blockIdx.y;
  int n0 = blockIdx.x * 64;
  int tid = threadIdx.x;
  int lane = tid & 63;
  int q = tid >> 6;
  const float* inb = in + ((size_t)b * nrows + n0) * 64;
#pragma unroll
  for (int i = 0; i < 16; ++i) {
    int n = q * 16 + i;
    t[n][lane] = inb[n * 64 + lane];
  }
  __syncthreads();
  unsigned short* outb = out + (size_t)b * 64 * nrows + n0;
  int pr = tid & 31, rq = tid >> 5;
#pragma unroll
  for (int i = 0; i < 8; ++i) {
    int r = rq + 8 * i;
    int n = 2 * pr;
    *(unsigned int*)(outb + (size_t)r * nrows + n) = cvtpk(t[n][r], t[n + 1][r]);
  }
}

// Gram: bmat[b] = T * T^T, T = [64, K] bf16 row-major. No atomics:
// 4 waves split K, LDS reduce. grid (B), block 256.
__global__ void gemm_gram2(const unsigned short* __restrict__ tT,
                           float* __restrict__ bmat, int K) {
  __shared__ float part[4][64][65];
  int b = blockIdx.x;
  int tid = threadIdx.x;
  int w = tid >> 6, l = tid & 63;
  int lr = l & 15, g = l >> 4;
  const unsigned short* vb = tT + (size_t)b * 64 * K;
  int kslice = K >> 2;
  int kbase = w * kslice;
  f32x4 acc[4][4] = {};
  for (int kk = 0; kk < kslice; kk += 32) {
    int k = kbase + kk + 8 * g;
    short8 fr[4];
#pragma unroll
    for (int rt = 0; rt < 4; ++rt)
      fr[rt] = *(const short8*)(vb + (size_t)(rt * 16 + lr) * K + k);
#pragma unroll
    for (int rt = 0; rt < 4; ++rt)
#pragma unroll
      for (int ct = 0; ct < 4; ++ct)
        acc[rt][ct] = __builtin_amdgcn_mfma_f32_16x16x32_bf16(fr[rt], fr[ct], acc[rt][ct], 0, 0, 0);
  }
#pragma unroll
  for (int rt = 0; rt < 4; ++rt)
#pragma unroll
    for (int ct = 0; ct < 4; ++ct)
#pragma unroll
      for (int j = 0; j < 4; ++j)
        part[w][rt * 16 + 4 * g + j][ct * 16 + lr] = acc[rt][ct][j];
  __syncthreads();
  float* bb = bmat + b * 4096;
  for (int i = tid; i < 4096; i += 256) {
    int row = i >> 6, col = i & 63;
    bb[i] = part[0][row][col] + part[1][row][col] + part[2][row][col] + part[3][row][col];
  }
}

// a[b][m][r] = sum_n x[b][m][n] * v[b][n][r];  vT = [B,64,N] bf16
// x rows DMA-staged via global_load_lds: [128 m][64 n] f32 tile (32 KB),
// double-buffered. Source pre-swizzled (16B slot ^= row&7), read applies
// the same XOR -> structural-optimal b128 reads. No K-split.
// grid (M/128, B), block 512 (8 waves; wave w owns rows w*16..+15).
__global__ void __launch_bounds__(512, 2)
gemm_xv(const float* __restrict__ x,
        const unsigned short* __restrict__ vT,
        float* __restrict__ a) {
  __shared__ char smem[65536];  // 2 x 32 KB stage buffers
  int b = blockIdx.y;
  int m0 = blockIdx.x * 128;
  int tid = threadIdx.x;
  int w = tid >> 6, l = tid & 63;
  int lr = l & 15, g = l >> 4;
  const unsigned short* vb = vT + (size_t)b * 64 * NN;
  const char* xg0 = (const char*)x + ((size_t)b * MM + m0) * (size_t)(NN * 4);
  f32x4 acc[4] = {};
  int rowb = (w * 16 + lr) * 256;  // this lane's A-row base in the tile
  int key = lr & 7;                // read-side swizzle key (= row&7)

#define XVSTAGE(DB, CH)                                                         \
  {                                                                             \
    char* lbs = (char*)smem + (DB)*32768;                                       \
    _Pragma("unroll")                                                           \
    for (int i = 0; i < 4; ++i) {                                               \
      int s = w * 4 + i;                                                        \
      int lg = ((l & 15) ^ ((s & 1) * 4 + (l >> 4))) * 16;                      \
      const char* gp = xg0 + (size_t)(s * 4 + (l >> 4)) * (NN * 4) +            \
                       (CH)*256 + lg;                                           \
      __builtin_amdgcn_global_load_lds(                                         \
          (const __attribute__((address_space(1))) unsigned int*)gp,            \
          (__attribute__((address_space(3))) unsigned int*)(lbs + s * 1024),    \
          16, 0, 0);                                                            \
    }                                                                           \
  }

  XVSTAGE(0, 0);
  __syncthreads();
  for (int c = 0; c < 32; ++c) {
    int db = c & 1;
    if (c + 1 < 32) XVSTAGE(db ^ 1, c + 1);
    const char* lb = (const char*)smem + db * 32768 + rowb;
#pragma unroll
    for (int kh = 0; kh < 2; ++kh) {
      f32x4 lo = *(const f32x4*)(lb + ((kh * 8 + 2 * g + 0) ^ key) * 16);
      f32x4 hi = *(const f32x4*)(lb + ((kh * 8 + 2 * g + 1) ^ key) * 16);
      union { short8 s; unsigned int u[4]; } af;
      af.u[0] = cvtpk(lo[0], lo[1]);
      af.u[1] = cvtpk(lo[2], lo[3]);
      af.u[2] = cvtpk(hi[0], hi[1]);
      af.u[3] = cvtpk(hi[2], hi[3]);
      int k = c * 64 + kh * 32 + 8 * g;
#pragma unroll
      for (int ct = 0; ct < 4; ++ct) {
        short8 bf = *(const short8*)(vb + (size_t)(ct * 16 + lr) * NN + k);
        acc[ct] = __builtin_amdgcn_mfma_f32_16x16x32_bf16(af.s, bf, acc[ct], 0, 0, 0);
      }
    }
    __syncthreads();  // drains vmcnt: stage(c+1) landed; all reads of db done
  }
#undef XVSTAGE

  float* ab = a + ((size_t)b * MM + m0 + w * 16) * 64;
#pragma unroll
  for (int ct = 0; ct < 4; ++ct)
#pragma unroll
    for (int j = 0; j < 4; ++j)
      ab[(size_t)(4 * g + j) * 64 + ct * 16 + lr] = acc[ct][j];
}

// a[b][n][r] = sum_m x[b][m][n] * u[b][m][r];  uT = [B,64,M] bf16
// x^T tile staged as f32 via global_load_lds, double-buffered.
// BATCH ORDER REVERSED for L3 hits on the second pass over x.
// grid (N/64, B), block 512; K-split 2 across wave halves.
__global__ void __launch_bounds__(512, 4)
gemm_xtu(const float* __restrict__ x,
         const unsigned short* __restrict__ uT,
         float* __restrict__ a) {
  __shared__ char smem[65536];  // [half][dbuf] 16KB stage tiles; red aliased after loop
  int b = (BB - 1) - blockIdx.y;   // reverse-order second pass over x
  int n0 = blockIdx.x * 64;
  int tid = threadIdx.x;
  int w = tid >> 6, l = tid & 63;
  int lr = l & 15, g = l >> 4;
  int half = w >> 2, wq = w & 3;
  int nr = wq * 16 + lr;  // A-row (n within tile)
  const unsigned short* ubh = uT + (size_t)b * 64 * MM + half * 1024;
  const char* xg0 = (const char*)x + (((size_t)b * MM + half * 1024) * NN + n0) * 4;
  f32x4 acc[4] = {};

#define STAGE(DB, CH)                                                                   \
  {                                                                                     \
    const char* xg = xg0 + (size_t)(CH) * 64 * (NN * 4);                                \
    char* lbs = smem + (half * 2 + (DB)) * 16384;                                       \
    _Pragma("unroll")                                                                   \
    for (int i = 0; i < 4; ++i) {                                                       \
      int g4 = wq * 4 + i;                                                              \
      int key = ((g4 >> 1) & 1) << 6;                                                   \
      const char* gp = xg + (size_t)(g4 * 4 + (l >> 4)) * (NN * 4) +                    \
                       (((l & 15) * 16) ^ key);                                         \
      __builtin_amdgcn_global_load_lds(                                                 \
          (const __attribute__((address_space(1))) unsigned int*)gp,                    \
          (__attribute__((address_space(3))) unsigned int*)(lbs + g4 * 1024), 16, 0, 0);\
    }                                                                                   \
  }

  STAGE(0, 0);
  __syncthreads();
  for (int c = 0; c < 16; ++c) {
    int db = c & 1;
    if (c + 1 < 16) STAGE(db ^ 1, c + 1);
    const char* lb = smem + (half * 2 + db) * 16384;
#pragma unroll
    for (int kh = 0; kh < 2; ++kh) {
      float vv[8];
#pragma unroll
      for (int j = 0; j < 8; ++j)
        vv[j] = *(const float*)(lb + (kh * 32 + 8 * g + j) * 256 + ((nr * 4) ^ ((g & 1) << 6)));
      union { short8 s; unsigned int u[4]; } af;
      af.u[0] = cvtpk(vv[0], vv[1]);
      af.u[1] = cvtpk(vv[2], vv[3]);
      af.u[2] = cvtpk(vv[4], vv[5]);
      af.u[3] = cvtpk(vv[6], vv[7]);
      int k = c * 64 + kh * 32 + 8 * g;
#pragma unroll
      for (int ct = 0; ct < 4; ++ct) {
        short8 bf = *(const short8*)(ubh + (size_t)(ct * 16 + lr) * MM + k);
        acc[ct] = __builtin_amdgcn_mfma_f32_16x16x32_bf16(af.s, bf, acc[ct], 0, 0, 0);
      }
    }
    __syncthreads();  // drains vmcnt: stage(c+1) landed; all reads of buf done
  }
#undef STAGE

  float (*red)[16][66] = (float (*)[16][66])smem;  // aliases dead stage buffers
  if (half) {
#pragma unroll
    for (int ct = 0; ct < 4; ++ct)
#pragma unroll
      for (int j = 0; j < 4; ++j)
        red[wq][4 * g + j][ct * 16 + lr] = acc[ct][j];
  }
  __syncthreads();
  if (!half) {
    float* ab = a + ((size_t)b * NN + n0 + wq * 16) * 64;
#pragma unroll
    for (int ct = 0; ct < 4; ++ct)
#pragma unroll
      for (int j = 0; j < 4; ++j)
        ab[(size_t)(4 * g + j) * 64 + ct * 16 + lr] =
            acc[ct][j] + red[wq][4 * g + j][ct * 16 + lr];
  }
}

// Coordinate descent, one THREAD per row: u[64], a[64] live in VGPRs,
// b reads are thread-invariant -> s_load + SGPR fmac operands. Each
// wave-instruction advances 64 rows (vs 1 in the wave-per-row scheme).
// Fully unrolled so u[r]/a[r] stay statically indexed (registers).
// grid (nrows/64, B), block 64 (1 wave).
__global__ void __launch_bounds__(64, 1)
cd_kernel2(const float* __restrict__ u_in,
           const float* __restrict__ a_ws,
           const float* __restrict__ bmat,
           float* __restrict__ u_out,
           float l1, float l2e, int nrows) {
  int b = blockIdx.y;
  int m = blockIdx.x * 64 + threadIdx.x;
  size_t base = ((size_t)b * nrows + m) * 64;
  const float* bb = bmat + b * 4096;
  float uu[64], aa[64];
#pragma unroll
  for (int i = 0; i < 16; ++i) {
    *(f32x4*)(uu + 4 * i) = *(const f32x4*)(u_in + base + 4 * i);
    *(f32x4*)(aa + 4 * i) = *(const f32x4*)(a_ws + base + 4 * i);
  }
  // lane j precomputes inv[j] = 1/(b[j][j]+l2e); consumed via readlane(r).
  int lane = threadIdx.x;
  float invl = 1.0f / (bb[lane * 65] + l2e);
#pragma unroll
  for (int r = 0; r < 64; ++r) {
    float s0 = 0.f, s1 = 0.f, s2 = 0.f, s3 = 0.f;
#pragma unroll
    for (int j = 0; j < 64; j += 4) {
      s0 = fmaf(uu[j + 0], bb[r * 64 + j + 0], s0);
      s1 = fmaf(uu[j + 1], bb[r * 64 + j + 1], s1);
      s2 = fmaf(uu[j + 2], bb[r * 64 + j + 2], s2);
      s3 = fmaf(uu[j + 3], bb[r * 64 + j + 3], s3);
    }
    float s = (s0 + s1) + (s2 + s3);
    float brr = bb[r * 65];                      // uniform -> SGPR
    float num = fmaf(uu[r], brr, aa[r] - s);     // a_r - (s - u_r*b_rr)
    float cl = fminf(fmaxf(num, -l1), l1);       // v_med3
    uu[r] = (num - cl) * rdlane(invl, r);        // soft-thr / (b_rr+l2e)
  }
#pragma unroll
  for (int i = 0; i < 16; ++i)
    *(f32x4*)(u_out + base + 4 * i) = *(const f32x4*)(uu + 4 * i);
}

extern "C" void kernel_launch(void* const* d_in, const int* in_sizes, int n_in,
                              void* d_out, int out_size, void* d_ws, size_t ws_size,
                              hipStream_t stream) {
  (void)in_sizes; (void)n_in; (void)out_size; (void)ws_size;
  const float* x = (const float*)d_in[0];
  const float* u = (const float*)d_in[1];
  const float* v = (const float*)d_in[2];
  float* u_out = (float*)d_out;
  float* v_out = u_out + (size_t)BB * MM * 64;

  float* a_ws = (float*)d_ws;                                        // 8.39 MB
  float* b_ws = (float*)((char*)d_ws + (size_t)BB * MM * 64 * 4);    // 256 KB
  unsigned short* tT = (unsigned short*)((char*)b_ws + (size_t)BB * 4096 * 4);

  float l1u = (float)(0.01 * 0.1 * (double)NN);
  float l2u = (float)(0.01 * 0.9 * (double)NN + 1e-16);
  float l1v = (float)(0.01 * 0.1 * (double)MM);
  float l2v = (float)(0.01 * 0.9 * (double)MM + 1e-16);

  // ---- factor 0: update u ----
  transpose_cvt<<<dim3(NN / 64, BB), 256, 0, stream>>>(v, tT, NN);
  gemm_gram2<<<dim3(BB), 256, 0, stream>>>(tT, b_ws, NN);
  gemm_xv<<<dim3(MM / 128, BB), 512, 0, stream>>>(x, tT, a_ws);
  cd_kernel2<<<dim3(MM / 64, BB), 64, 0, stream>>>(u, a_ws, b_ws, u_out, l1u, l2u, MM);

  // ---- factor 1: update v (uses new u) ----
  transpose_cvt<<<dim3(MM / 64, BB), 256, 0, stream>>>(u_out, tT, MM);
  gemm_gram2<<<dim3(BB), 256, 0, stream>>>(tT, b_ws, MM);
  gemm_xtu<<<dim3(NN / 64, BB), 512, 0, stream>>>(x, tT, a_ws);
  cd_kernel2<<<dim3(NN / 64, BB), 64, 0, stream>>>(v, a_ws, b_ws, v_out, l1v, l2v, NN);
}

// Round 8
// 257.101 us; speedup vs baseline: 1.4304x; 1.0099x over previous
//
#include <hip/hip_runtime.h>

typedef __attribute__((ext_vector_type(8))) short short8;
typedef __attribute__((ext_vector_type(4))) float f32x4;

#define BB 16
#define MM 2048
#define NN 2048

static __device__ __forceinline__ unsigned int cvtpk(float lo, float hi) {
  unsigned int r;
  asm("v_cvt_pk_bf16_f32 %0, %1, %2" : "=v"(r) : "v"(lo), "v"(hi));
  return r;
}
static __device__ __forceinline__ float rdlane(float v, int l) {
  return __uint_as_float(__builtin_amdgcn_readlane(__float_as_uint(v), l));
}

// in: [B, nrows, 64] f32 -> out: [B, 64, nrows] bf16
__global__ void transpose_cvt(const float* __restrict__ in,
                              unsigned short* __restrict__ out, int nrows) {
  __shared__ float t[64][65];
  int b = blockIdx.y;
  int n0 = blockIdx.x * 64;
  int tid = threadIdx.x;
  int lane = tid & 63;
  int q = tid >> 6;
  const float* inb = in + ((size_t)b * nrows + n0) * 64;
#pragma unroll
  for (int i = 0; i < 16; ++i) {
    int n = q * 16 + i;
    t[n][lane] = inb[n * 64 + lane];
  }
  __syncthreads();
  unsigned short* outb = out + (size_t)b * 64 * nrows + n0;
  int pr = tid & 31, rq = tid >> 5;
#pragma unroll
  for (int i = 0; i < 8; ++i) {
    int r = rq + 8 * i;
    int n = 2 * pr;
    *(unsigned int*)(outb + (size_t)r * nrows + n) = cvtpk(t[n][r], t[n + 1][r]);
  }
}

// Gram: bmat[b] = T * T^T, T = [64, K] bf16 row-major. No atomics:
// 4 waves split K, LDS reduce. grid (B), block 256.
__global__ void gemm_gram2(const unsigned short* __restrict__ tT,
                           float* __restrict__ bmat, int K) {
  __shared__ float part[4][64][65];
  int b = blockIdx.x;
  int tid = threadIdx.x;
  int w = tid >> 6, l = tid & 63;
  int lr = l & 15, g = l >> 4;
  const unsigned short* vb = tT + (size_t)b * 64 * K;
  int kslice = K >> 2;
  int kbase = w * kslice;
  f32x4 acc[4][4] = {};
  for (int kk = 0; kk < kslice; kk += 32) {
    int k = kbase + kk + 8 * g;
    short8 fr[4];
#pragma unroll
    for (int rt = 0; rt < 4; ++rt)
      fr[rt] = *(const short8*)(vb + (size_t)(rt * 16 + lr) * K + k);
#pragma unroll
    for (int rt = 0; rt < 4; ++rt)
#pragma unroll
      for (int ct = 0; ct < 4; ++ct)
        acc[rt][ct] = __builtin_amdgcn_mfma_f32_16x16x32_bf16(fr[rt], fr[ct], acc[rt][ct], 0, 0, 0);
  }
#pragma unroll
  for (int rt = 0; rt < 4; ++rt)
#pragma unroll
    for (int ct = 0; ct < 4; ++ct)
#pragma unroll
      for (int j = 0; j < 4; ++j)
        part[w][rt * 16 + 4 * g + j][ct * 16 + lr] = acc[rt][ct][j];
  __syncthreads();
  float* bb = bmat + b * 4096;
  for (int i = tid; i < 4096; i += 256) {
    int row = i >> 6, col = i & 63;
    bb[i] = part[0][row][col] + part[1][row][col] + part[2][row][col] + part[3][row][col];
  }
}

// a[b][m][r] = sum_n x[b][m][n] * v[b][n][r];  vT = [B,64,N] bf16
// x rows DMA-staged via global_load_lds: [128 m][64 n] f32 tile (32 KB),
// double-buffered. Source pre-swizzled (16B slot ^= row&7), read applies
// the same XOR. grid (M/128, B), block 512.
__global__ void __launch_bounds__(512, 2)
gemm_xv(const float* __restrict__ x,
        const unsigned short* __restrict__ vT,
        float* __restrict__ a) {
  __shared__ char smem[65536];  // 2 x 32 KB stage buffers
  int b = blockIdx.y;
  int m0 = blockIdx.x * 128;
  int tid = threadIdx.x;
  int w = tid >> 6, l = tid & 63;
  int lr = l & 15, g = l >> 4;
  const unsigned short* vb = vT + (size_t)b * 64 * NN;
  const char* xg0 = (const char*)x + ((size_t)b * MM + m0) * (size_t)(NN * 4);
  f32x4 acc[4] = {};
  int rowb = (w * 16 + lr) * 256;  // this lane's A-row base in the tile
  int key = lr & 7;                // read-side swizzle key (= row&7)

#define XVSTAGE(DB, CH)                                                         \
  {                                                                             \
    char* lbs = (char*)smem + (DB)*32768;                                       \
    _Pragma("unroll")                                                           \
    for (int i = 0; i < 4; ++i) {                                               \
      int s = w * 4 + i;                                                        \
      int lg = ((l & 15) ^ ((s & 1) * 4 + (l >> 4))) * 16;                      \
      const char* gp = xg0 + (size_t)(s * 4 + (l >> 4)) * (NN * 4) +            \
                       (CH)*256 + lg;                                           \
      __builtin_amdgcn_global_load_lds(                                         \
          (const __attribute__((address_space(1))) unsigned int*)gp,            \
          (__attribute__((address_space(3))) unsigned int*)(lbs + s * 1024),    \
          16, 0, 0);                                                            \
    }                                                                           \
  }

  XVSTAGE(0, 0);
  __syncthreads();
  for (int c = 0; c < 32; ++c) {
    int db = c & 1;
    if (c + 1 < 32) XVSTAGE(db ^ 1, c + 1);
    const char* lb = (const char*)smem + db * 32768 + rowb;
#pragma unroll
    for (int kh = 0; kh < 2; ++kh) {
      f32x4 lo = *(const f32x4*)(lb + ((kh * 8 + 2 * g + 0) ^ key) * 16);
      f32x4 hi = *(const f32x4*)(lb + ((kh * 8 + 2 * g + 1) ^ key) * 16);
      union { short8 s; unsigned int u[4]; } af;
      af.u[0] = cvtpk(lo[0], lo[1]);
      af.u[1] = cvtpk(lo[2], lo[3]);
      af.u[2] = cvtpk(hi[0], hi[1]);
      af.u[3] = cvtpk(hi[2], hi[3]);
      int k = c * 64 + kh * 32 + 8 * g;
#pragma unroll
      for (int ct = 0; ct < 4; ++ct) {
        short8 bf = *(const short8*)(vb + (size_t)(ct * 16 + lr) * NN + k);
        acc[ct] = __builtin_amdgcn_mfma_f32_16x16x32_bf16(af.s, bf, acc[ct], 0, 0, 0);
      }
    }
    __syncthreads();  // drains vmcnt: stage(c+1) landed; all reads of db done
  }
#undef XVSTAGE

  float* ab = a + ((size_t)b * MM + m0 + w * 16) * 64;
#pragma unroll
  for (int ct = 0; ct < 4; ++ct)
#pragma unroll
    for (int j = 0; j < 4; ++j)
      ab[(size_t)(4 * g + j) * 64 + ct * 16 + lr] = acc[ct][j];
}

// a[b][n][r] = sum_m x[b][m][n] * u[b][m][r];  uT = [B,64,M] bf16
// WIDE-N: block covers 128 n; stages [64 m][128 n] f32 (32 KB) tiles,
// double-buffered -> 512B contiguous per x-row per request (was 64B).
// Swizzle: 16B slot' = slot ^ (((m>>3)&1)<<2), source-side + read-side.
// grid (N/128, B), block 512 (8 waves; wave w owns n = w*16..+15).
__global__ void __launch_bounds__(512, 2)
gemm_xtu(const float* __restrict__ x,
         const unsigned short* __restrict__ uT,
         float* __restrict__ a) {
  __shared__ char smem[65536];  // 2 x 32 KB stage buffers
  int b = (BB - 1) - blockIdx.y;   // reverse-order second pass over x (L3)
  int n0 = blockIdx.x * 128;
  int tid = threadIdx.x;
  int w = tid >> 6, l = tid & 63;
  int lr = l & 15, g = l >> 4;
  const unsigned short* ub = uT + (size_t)b * 64 * MM;
  const char* xg0 = (const char*)x + ((size_t)b * MM * NN + n0) * 4;
  f32x4 acc[4] = {};
  int slotX = ((w * 4 + (lr >> 2)) ^ ((g & 1) << 2)) * 16 + (lr & 3) * 4;

  // Stage chunk CH (m-rows CH*64..+63, all 128 n) into buffer DB.
  // Instr covers 2 rows (32 lanes x 16B each); dest linear, source slot
  // XOR'd by ((row>>3)&1)<<2.
#define XTSTAGE(DB, CH)                                                         \
  {                                                                             \
    char* lbs = (char*)smem + (DB)*32768;                                       \
    _Pragma("unroll")                                                           \
    for (int i = 0; i < 4; ++i) {                                               \
      int rr = 2 * (4 * w + i) + (l >> 5);                                      \
      int sl = (l & 31) ^ (((rr >> 3) & 1) << 2);                               \
      const char* gp = xg0 + (size_t)((CH)*64 + rr) * (NN * 4) + sl * 16;       \
      __builtin_amdgcn_global_load_lds(                                         \
          (const __attribute__((address_space(1))) unsigned int*)gp,            \
          (__attribute__((address_space(3))) unsigned int*)(lbs + (4*w+i)*1024),\
          16, 0, 0);                                                            \
    }                                                                           \
  }

  XTSTAGE(0, 0);
  __syncthreads();
  for (int c = 0; c < 32; ++c) {
    int db = c & 1;
    if (c + 1 < 32) XTSTAGE(db ^ 1, c + 1);
    const char* lb = (const char*)smem + db * 32768 + slotX;
#pragma unroll
    for (int kh = 0; kh < 2; ++kh) {
      const char* lk = lb + (kh * 32 + 8 * g) * 512;
      float vv[8];
#pragma unroll
      for (int j = 0; j < 8; ++j)
        vv[j] = *(const float*)(lk + j * 512);
      union { short8 s; unsigned int u[4]; } af;
      af.u[0] = cvtpk(vv[0], vv[1]);
      af.u[1] = cvtpk(vv[2], vv[3]);
      af.u[2] = cvtpk(vv[4], vv[5]);
      af.u[3] = cvtpk(vv[6], vv[7]);
      int k = c * 64 + kh * 32 + 8 * g;
#pragma unroll
      for (int ct = 0; ct < 4; ++ct) {
        short8 bf = *(const short8*)(ub + (size_t)(ct * 16 + lr) * MM + k);
        acc[ct] = __builtin_amdgcn_mfma_f32_16x16x32_bf16(af.s, bf, acc[ct], 0, 0, 0);
      }
    }
    __syncthreads();  // drains vmcnt: stage(c+1) landed; all reads of db done
  }
#undef XTSTAGE

  float* ab = a + ((size_t)b * NN + n0 + w * 16) * 64;
#pragma unroll
  for (int ct = 0; ct < 4; ++ct)
#pragma unroll
    for (int j = 0; j < 4; ++j)
      ab[(size_t)(4 * g + j) * 64 + ct * 16 + lr] = acc[ct][j];
}

// Coordinate descent, one THREAD per row: u[64], a[64] live in VGPRs,
// b reads are thread-invariant -> s_load + SGPR fmac operands.
// grid (nrows/64, B), block 64 (1 wave).
__global__ void __launch_bounds__(64, 1)
cd_kernel2(const float* __restrict__ u_in,
           const float* __restrict__ a_ws,
           const float* __restrict__ bmat,
           float* __restrict__ u_out,
           float l1, float l2e, int nrows) {
  int b = blockIdx.y;
  int m = blockIdx.x * 64 + threadIdx.x;
  size_t base = ((size_t)b * nrows + m) * 64;
  const float* bb = bmat + b * 4096;
  float uu[64], aa[64];
#pragma unroll
  for (int i = 0; i < 16; ++i) {
    *(f32x4*)(uu + 4 * i) = *(const f32x4*)(u_in + base + 4 * i);
    *(f32x4*)(aa + 4 * i) = *(const f32x4*)(a_ws + base + 4 * i);
  }
  int lane = threadIdx.x;
  float invl = 1.0f / (bb[lane * 65] + l2e);
#pragma unroll
  for (int r = 0; r < 64; ++r) {
    float s0 = 0.f, s1 = 0.f, s2 = 0.f, s3 = 0.f;
#pragma unroll
    for (int j = 0; j < 64; j += 4) {
      s0 = fmaf(uu[j + 0], bb[r * 64 + j + 0], s0);
      s1 = fmaf(uu[j + 1], bb[r * 64 + j + 1], s1);
      s2 = fmaf(uu[j + 2], bb[r * 64 + j + 2], s2);
      s3 = fmaf(uu[j + 3], bb[r * 64 + j + 3], s3);
    }
    float s = (s0 + s1) + (s2 + s3);
    float brr = bb[r * 65];                      // uniform -> SGPR
    float num = fmaf(uu[r], brr, aa[r] - s);     // a_r - (s - u_r*b_rr)
    float cl = fminf(fmaxf(num, -l1), l1);       // v_med3
    uu[r] = (num - cl) * rdlane(invl, r);        // soft-thr / (b_rr+l2e)
  }
#pragma unroll
  for (int i = 0; i < 16; ++i)
    *(f32x4*)(u_out + base + 4 * i) = *(const f32x4*)(uu + 4 * i);
}

extern "C" void kernel_launch(void* const* d_in, const int* in_sizes, int n_in,
                              void* d_out, int out_size, void* d_ws, size_t ws_size,
                              hipStream_t stream) {
  (void)in_sizes; (void)n_in; (void)out_size; (void)ws_size;
  const float* x = (const float*)d_in[0];
  const float* u = (const float*)d_in[1];
  const float* v = (const float*)d_in[2];
  float* u_out = (float*)d_out;
  float* v_out = u_out + (size_t)BB * MM * 64;

  float* a_ws = (float*)d_ws;                                        // 8.39 MB
  float* b_ws = (float*)((char*)d_ws + (size_t)BB * MM * 64 * 4);    // 256 KB
  unsigned short* tT = (unsigned short*)((char*)b_ws + (size_t)BB * 4096 * 4);

  float l1u = (float)(0.01 * 0.1 * (double)NN);
  float l2u = (float)(0.01 * 0.9 * (double)NN + 1e-16);
  float l1v = (float)(0.01 * 0.1 * (double)MM);
  float l2v = (float)(0.01 * 0.9 * (double)MM + 1e-16);

  // ---- factor 0: update u ----
  transpose_cvt<<<dim3(NN / 64, BB), 256, 0, stream>>>(v, tT, NN);
  gemm_gram2<<<dim3(BB), 256, 0, stream>>>(tT, b_ws, NN);
  gemm_xv<<<dim3(MM / 128, BB), 512, 0, stream>>>(x, tT, a_ws);
  cd_kernel2<<<dim3(MM / 64, BB), 64, 0, stream>>>(u, a_ws, b_ws, u_out, l1u, l2u, MM);

  // ---- factor 1: update v (uses new u) ----
  transpose_cvt<<<dim3(MM / 64, BB), 256, 0, stream>>>(u_out, tT, MM);
  gemm_gram2<<<dim3(BB), 256, 0, stream>>>(tT, b_ws, MM);
  gemm_xtu<<<dim3(NN / 128, BB), 512, 0, stream>>>(x, tT, a_ws);
  cd_kernel2<<<dim3(NN / 64, BB), 64, 0, stream>>>(v, a_ws, b_ws, v_out, l1v, l2v, NN);
}

// Round 9
// 255.340 us; speedup vs baseline: 1.4403x; 1.0069x over previous
//
#include <hip/hip_runtime.h>

typedef __attribute__((ext_vector_type(8))) short short8;
typedef __attribute__((ext_vector_type(4))) float f32x4;

#define BB 16
#define MM 2048
#define NN 2048

static __device__ __forceinline__ unsigned int cvtpk(float lo, float hi) {
  unsigned int r;
  asm("v_cvt_pk_bf16_f32 %0, %1, %2" : "=v"(r) : "v"(lo), "v"(hi));
  return r;
}
static __device__ __forceinline__ float rdlane(float v, int l) {
  return __uint_as_float(__builtin_amdgcn_readlane(__float_as_uint(v), l));
}

// in: [B, nrows, 64] f32 -> out: [B, 64, nrows] bf16
__global__ void transpose_cvt(const float* __restrict__ in,
                              unsigned short* __restrict__ out, int nrows) {
  __shared__ float t[64][65];
  int b = blockIdx.y;
  int n0 = blockIdx.x * 64;
  int tid = threadIdx.x;
  int lane = tid & 63;
  int q = tid >> 6;
  const float* inb = in + ((size_t)b * nrows + n0) * 64;
#pragma unroll
  for (int i = 0; i < 16; ++i) {
    int n = q * 16 + i;
    t[n][lane] = inb[n * 64 + lane];
  }
  __syncthreads();
  unsigned short* outb = out + (size_t)b * 64 * nrows + n0;
  int pr = tid & 31, rq = tid >> 5;
#pragma unroll
  for (int i = 0; i < 8; ++i) {
    int r = rq + 8 * i;
    int n = 2 * pr;
    *(unsigned int*)(outb + (size_t)r * nrows + n) = cvtpk(t[n][r], t[n + 1][r]);
  }
}

// Gram: bmat[b] = T * T^T, T = [64, K] bf16 row-major. No atomics:
// 4 waves split K, LDS reduce. grid (B), block 256.
__global__ void gemm_gram2(const unsigned short* __restrict__ tT,
                           float* __restrict__ bmat, int K) {
  __shared__ float part[4][64][65];
  int b = blockIdx.x;
  int tid = threadIdx.x;
  int w = tid >> 6, l = tid & 63;
  int lr = l & 15, g = l >> 4;
  const unsigned short* vb = tT + (size_t)b * 64 * K;
  int kslice = K >> 2;
  int kbase = w * kslice;
  f32x4 acc[4][4] = {};
  for (int kk = 0; kk < kslice; kk += 32) {
    int k = kbase + kk + 8 * g;
    short8 fr[4];
#pragma unroll
    for (int rt = 0; rt < 4; ++rt)
      fr[rt] = *(const short8*)(vb + (size_t)(rt * 16 + lr) * K + k);
#pragma unroll
    for (int rt = 0; rt < 4; ++rt)
#pragma unroll
      for (int ct = 0; ct < 4; ++ct)
        acc[rt][ct] = __builtin_amdgcn_mfma_f32_16x16x32_bf16(fr[rt], fr[ct], acc[rt][ct], 0, 0, 0);
  }
#pragma unroll
  for (int rt = 0; rt < 4; ++rt)
#pragma unroll
    for (int ct = 0; ct < 4; ++ct)
#pragma unroll
      for (int j = 0; j < 4; ++j)
        part[w][rt * 16 + 4 * g + j][ct * 16 + lr] = acc[rt][ct][j];
  __syncthreads();
  float* bb = bmat + b * 4096;
  for (int i = tid; i < 4096; i += 256) {
    int row = i >> 6, col = i & 63;
    bb[i] = part[0][row][col] + part[1][row][col] + part[2][row][col] + part[3][row][col];
  }
}

// a[b][m][r] = sum_n x[b][m][n] * v[b][n][r];  vT = [B,64,N] bf16
// [64 m][64 n] f32 tiles DMA-staged (16 KB, double-buffered), 4 waves,
// grid (M/64, B) = 512 blocks -> 2 blocks/CU so one block's compute covers
// the other block's barrier-drain. Source pre-swizzled (slot ^= row&7),
// read applies the same XOR.
__global__ void __launch_bounds__(256, 2)
gemm_xv(const float* __restrict__ x,
        const unsigned short* __restrict__ vT,
        float* __restrict__ a) {
  __shared__ char smem[32768];  // 2 x 16 KB stage buffers
  int b = blockIdx.y;
  int m0 = blockIdx.x * 64;
  int tid = threadIdx.x;
  int w = tid >> 6, l = tid & 63;
  int lr = l & 15, g = l >> 4;
  const unsigned short* vb = vT + (size_t)b * 64 * NN;
  const char* xg0 = (const char*)x + ((size_t)b * MM + m0) * (size_t)(NN * 4);
  f32x4 acc[4] = {};
  int rowb = (w * 16 + lr) * 256;  // this lane's A-row base in the tile
  int key = lr & 7;                // read-side swizzle key (= row&7)

  // 16 insts x 1 KB; inst s covers rows s*4+(l>>4), 256 B each.
#define XVSTAGE(DB, CH)                                                         \
  {                                                                             \
    char* lbs = (char*)smem + (DB)*16384;                                       \
    _Pragma("unroll")                                                           \
    for (int i = 0; i < 4; ++i) {                                               \
      int s = w * 4 + i;                                                        \
      int lg = ((l & 15) ^ ((s & 1) * 4 + (l >> 4))) * 16;                      \
      const char* gp = xg0 + (size_t)(s * 4 + (l >> 4)) * (NN * 4) +            \
                       (CH)*256 + lg;                                           \
      __builtin_amdgcn_global_load_lds(                                         \
          (const __attribute__((address_space(1))) unsigned int*)gp,            \
          (__attribute__((address_space(3))) unsigned int*)(lbs + s * 1024),    \
          16, 0, 0);                                                            \
    }                                                                           \
  }

  XVSTAGE(0, 0);
  __syncthreads();
  for (int c = 0; c < 32; ++c) {
    int db = c & 1;
    if (c + 1 < 32) XVSTAGE(db ^ 1, c + 1);
    const char* lb = (const char*)smem + db * 16384 + rowb;
#pragma unroll
    for (int kh = 0; kh < 2; ++kh) {
      f32x4 lo = *(const f32x4*)(lb + ((kh * 8 + 2 * g + 0) ^ key) * 16);
      f32x4 hi = *(const f32x4*)(lb + ((kh * 8 + 2 * g + 1) ^ key) * 16);
      union { short8 s; unsigned int u[4]; } af;
      af.u[0] = cvtpk(lo[0], lo[1]);
      af.u[1] = cvtpk(lo[2], lo[3]);
      af.u[2] = cvtpk(hi[0], hi[1]);
      af.u[3] = cvtpk(hi[2], hi[3]);
      int k = c * 64 + kh * 32 + 8 * g;
#pragma unroll
      for (int ct = 0; ct < 4; ++ct) {
        short8 bf = *(const short8*)(vb + (size_t)(ct * 16 + lr) * NN + k);
        acc[ct] = __builtin_amdgcn_mfma_f32_16x16x32_bf16(af.s, bf, acc[ct], 0, 0, 0);
      }
    }
    __syncthreads();  // stage(c+1) landed; all reads of db done
  }
#undef XVSTAGE

  float* ab = a + ((size_t)b * MM + m0 + w * 16) * 64;
#pragma unroll
  for (int ct = 0; ct < 4; ++ct)
#pragma unroll
    for (int j = 0; j < 4; ++j)
      ab[(size_t)(4 * g + j) * 64 + ct * 16 + lr] = acc[ct][j];
}

// a[b][n][r] = sum_m x[b][m][n] * u[b][m][r];  uT = [B,64,M] bf16
// [64 m][64 n] f32 x^T tiles staged (16 KB, dbuf), 4 waves, grid (N/64, B)
// = 512 blocks -> 2 blocks/CU. Column reads: slot ^= ((m>>3)&1)<<2 on both
// source and read side -> 2 lanes/bank. Batch order reversed for L3 hits.
__global__ void __launch_bounds__(256, 2)
gemm_xtu(const float* __restrict__ x,
         const unsigned short* __restrict__ uT,
         float* __restrict__ a) {
  __shared__ char smem[32768];  // 2 x 16 KB stage buffers
  int b = (BB - 1) - blockIdx.y;   // reverse-order second pass over x (L3)
  int n0 = blockIdx.x * 64;
  int tid = threadIdx.x;
  int w = tid >> 6, l = tid & 63;
  int lr = l & 15, g = l >> 4;
  const unsigned short* ub = uT + (size_t)b * 64 * MM;
  const char* xg0 = (const char*)x + ((size_t)b * MM * NN + n0) * 4;
  f32x4 acc[4] = {};
  // lane's column n = w*16+lr; logical slot = w*4+(lr>>2); XOR key = (g&1)<<2
  int slotX = ((w * 4 + (lr >> 2)) ^ ((g & 1) << 2)) * 16 + (lr & 3) * 4;

  // inst s covers m-rows s*4+(l>>4) of the chunk; source slot ^= ((row>>3)&1)<<2
#define XTSTAGE(DB, CH)                                                         \
  {                                                                             \
    char* lbs = (char*)smem + (DB)*16384;                                       \
    _Pragma("unroll")                                                           \
    for (int i = 0; i < 4; ++i) {                                               \
      int s = w * 4 + i;                                                        \
      int lg = ((l & 15) ^ (((s >> 1) & 1) << 2)) * 16;                         \
      const char* gp = xg0 + (size_t)((CH)*64 + s * 4 + (l >> 4)) * (NN * 4) +  \
                       lg;                                                      \
      __builtin_amdgcn_global_load_lds(                                         \
          (const __attribute__((address_space(1))) unsigned int*)gp,            \
          (__attribute__((address_space(3))) unsigned int*)(lbs + s * 1024),    \
          16, 0, 0);                                                            \
    }                                                                           \
  }

  XTSTAGE(0, 0);
  __syncthreads();
  for (int c = 0; c < 32; ++c) {
    int db = c & 1;
    if (c + 1 < 32) XTSTAGE(db ^ 1, c + 1);
    const char* lb = (const char*)smem + db * 16384 + slotX;
#pragma unroll
    for (int kh = 0; kh < 2; ++kh) {
      const char* lk = lb + (kh * 32 + 8 * g) * 256;
      float vv[8];
#pragma unroll
      for (int j = 0; j < 8; ++j)
        vv[j] = *(const float*)(lk + j * 256);
      union { short8 s; unsigned int u[4]; } af;
      af.u[0] = cvtpk(vv[0], vv[1]);
      af.u[1] = cvtpk(vv[2], vv[3]);
      af.u[2] = cvtpk(vv[4], vv[5]);
      af.u[3] = cvtpk(vv[6], vv[7]);
      int k = c * 64 + kh * 32 + 8 * g;
#pragma unroll
      for (int ct = 0; ct < 4; ++ct) {
        short8 bf = *(const short8*)(ub + (size_t)(ct * 16 + lr) * MM + k);
        acc[ct] = __builtin_amdgcn_mfma_f32_16x16x32_bf16(af.s, bf, acc[ct], 0, 0, 0);
      }
    }
    __syncthreads();  // stage(c+1) landed; all reads of db done
  }
#undef XTSTAGE

  float* ab = a + ((size_t)b * NN + n0 + w * 16) * 64;
#pragma unroll
  for (int ct = 0; ct < 4; ++ct)
#pragma unroll
    for (int j = 0; j < 4; ++j)
      ab[(size_t)(4 * g + j) * 64 + ct * 16 + lr] = acc[ct][j];
}

// Coordinate descent, one THREAD per row: u[64], a[64] live in VGPRs,
// b reads are thread-invariant -> s_load + SGPR fmac operands.
// grid (nrows/64, B), block 64 (1 wave).
__global__ void __launch_bounds__(64, 1)
cd_kernel2(const float* __restrict__ u_in,
           const float* __restrict__ a_ws,
           const float* __restrict__ bmat,
           float* __restrict__ u_out,
           float l1, float l2e, int nrows) {
  int b = blockIdx.y;
  int m = blockIdx.x * 64 + threadIdx.x;
  size_t base = ((size_t)b * nrows + m) * 64;
  const float* bb = bmat + b * 4096;
  float uu[64], aa[64];
#pragma unroll
  for (int i = 0; i < 16; ++i) {
    *(f32x4*)(uu + 4 * i) = *(const f32x4*)(u_in + base + 4 * i);
    *(f32x4*)(aa + 4 * i) = *(const f32x4*)(a_ws + base + 4 * i);
  }
  int lane = threadIdx.x;
  float invl = 1.0f / (bb[lane * 65] + l2e);
#pragma unroll
  for (int r = 0; r < 64; ++r) {
    float s0 = 0.f, s1 = 0.f, s2 = 0.f, s3 = 0.f;
#pragma unroll
    for (int j = 0; j < 64; j += 4) {
      s0 = fmaf(uu[j + 0], bb[r * 64 + j + 0], s0);
      s1 = fmaf(uu[j + 1], bb[r * 64 + j + 1], s1);
      s2 = fmaf(uu[j + 2], bb[r * 64 + j + 2], s2);
      s3 = fmaf(uu[j + 3], bb[r * 64 + j + 3], s3);
    }
    float s = (s0 + s1) + (s2 + s3);
    float brr = bb[r * 65];                      // uniform -> SGPR
    float num = fmaf(uu[r], brr, aa[r] - s);     // a_r - (s - u_r*b_rr)
    float cl = fminf(fmaxf(num, -l1), l1);       // v_med3
    uu[r] = (num - cl) * rdlane(invl, r);        // soft-thr / (b_rr+l2e)
  }
#pragma unroll
  for (int i = 0; i < 16; ++i)
    *(f32x4*)(u_out + base + 4 * i) = *(const f32x4*)(uu + 4 * i);
}

extern "C" void kernel_launch(void* const* d_in, const int* in_sizes, int n_in,
                              void* d_out, int out_size, void* d_ws, size_t ws_size,
                              hipStream_t stream) {
  (void)in_sizes; (void)n_in; (void)out_size; (void)ws_size;
  const float* x = (const float*)d_in[0];
  const float* u = (const float*)d_in[1];
  const float* v = (const float*)d_in[2];
  float* u_out = (float*)d_out;
  float* v_out = u_out + (size_t)BB * MM * 64;

  float* a_ws = (float*)d_ws;                                        // 8.39 MB
  float* b_ws = (float*)((char*)d_ws + (size_t)BB * MM * 64 * 4);    // 256 KB
  unsigned short* tT = (unsigned short*)((char*)b_ws + (size_t)BB * 4096 * 4);

  float l1u = (float)(0.01 * 0.1 * (double)NN);
  float l2u = (float)(0.01 * 0.9 * (double)NN + 1e-16);
  float l1v = (float)(0.01 * 0.1 * (double)MM);
  float l2v = (float)(0.01 * 0.9 * (double)MM + 1e-16);

  // ---- factor 0: update u ----
  transpose_cvt<<<dim3(NN / 64, BB), 256, 0, stream>>>(v, tT, NN);
  gemm_gram2<<<dim3(BB), 256, 0, stream>>>(tT, b_ws, NN);
  gemm_xv<<<dim3(MM / 64, BB), 256, 0, stream>>>(x, tT, a_ws);
  cd_kernel2<<<dim3(MM / 64, BB), 64, 0, stream>>>(u, a_ws, b_ws, u_out, l1u, l2u, MM);

  // ---- factor 1: update v (uses new u) ----
  transpose_cvt<<<dim3(MM / 64, BB), 256, 0, stream>>>(u_out, tT, MM);
  gemm_gram2<<<dim3(BB), 256, 0, stream>>>(tT, b_ws, MM);
  gemm_xtu<<<dim3(NN / 64, BB), 256, 0, stream>>>(x, tT, a_ws);
  cd_kernel2<<<dim3(NN / 64, BB), 64, 0, stream>>>(v, a_ws, b_ws, v_out, l1v, l2v, NN);
}